// Round 1
// baseline (3491.044 us; speedup 1.0000x reference)
//
#include <hip/hip_runtime.h>

#define Bn 4
#define Nn_ 2048
#define Dd 1024
#define Hh 8
#define HDd 64
#define Tt 8192   // Bn*Nn_

__device__ __forceinline__ void block_reduce2(float& a, float& b, float* sc) {
#pragma unroll
  for (int off = 32; off > 0; off >>= 1) {
    a += __shfl_down(a, off, 64);
    b += __shfl_down(b, off, 64);
  }
  __syncthreads();
  if ((threadIdx.x & 63) == 0) { int wid = threadIdx.x >> 6; sc[wid] = a; sc[4 + wid] = b; }
  __syncthreads();
  a = sc[0] + sc[1] + sc[2] + sc[3];
  b = sc[4] + sc[5] + sc[6] + sc[7];
}

__device__ __forceinline__ float gelu_f(float u) {
  const float c = 0.7978845608028654f * (u + 0.044715f * u * u * u);
  const float e = __expf(2.0f * c);
  const float th = 1.0f - 2.0f / (1.0f + e);
  return 0.5f * u * (1.0f + th);
}

// ---------- LN1 + potential projection (V, gamma) ----------
__global__ __launch_bounds__(256) void k_ln_pot(
    const float* __restrict__ x, const float* __restrict__ g, const float* __restrict__ bt,
    const float* __restrict__ w_pot, const float* __restrict__ b_pot,
    float* __restrict__ V, float* __restrict__ gam) {
  __shared__ float sc[8];
  const int m = blockIdx.x, t = threadIdx.x;
  const float4 xv = ((const float4*)(x + (size_t)m * Dd))[t];
  float s = xv.x + xv.y + xv.z + xv.w;
  float ss = fmaf(xv.x, xv.x, fmaf(xv.y, xv.y, fmaf(xv.z, xv.z, xv.w * xv.w)));
  block_reduce2(s, ss, sc);
  const float mean = s * (1.0f / Dd);
  const float var = ss * (1.0f / Dd) - mean * mean;
  const float rs = rsqrtf(var + 1e-5f);
  const float4 gv = ((const float4*)g)[t];
  const float4 bv = ((const float4*)bt)[t];
  const float xn0 = (xv.x - mean) * rs * gv.x + bv.x;
  const float xn1 = (xv.y - mean) * rs * gv.y + bv.y;
  const float xn2 = (xv.z - mean) * rs * gv.z + bv.z;
  const float xn3 = (xv.w - mean) * rs * gv.w + bv.w;
  const float4 wp0 = ((const float4*)w_pot)[t * 2];
  const float4 wp1 = ((const float4*)w_pot)[t * 2 + 1];
  float s0 = xn0 * wp0.x + xn1 * wp0.z + xn2 * wp1.x + xn3 * wp1.z;
  float s1 = xn0 * wp0.y + xn1 * wp0.w + xn2 * wp1.y + xn3 * wp1.w;
  block_reduce2(s0, s1, sc);
  if (t == 0) {
    V[m] = s0 + b_pot[0];
    const float p1 = s1 + b_pot[1];
    const float sp = fmaxf(p1, 0.0f) + log1pf(expf(-fabsf(p1)));
    gam[m] = sp + 0.1f;
  }
}

// ---------- continued fraction scans (serial; 8 independent chains) ----------
__global__ void k_cf(const float* __restrict__ V, const float* __restrict__ gam,
                     float* __restrict__ aRe, float* __restrict__ aIm,
                     float* __restrict__ bRe, float* __restrict__ bIm) {
  if (threadIdx.x != 0) return;
  const int b = blockIdx.x >> 1, dir = blockIdx.x & 1;
  const float* Vb = V + b * Nn_;
  const float* gb = gam + b * Nn_;
  if (dir == 0) {
    float cr = Vb[0] + 2.0f, ci = -gb[0];
    aRe[b * Nn_] = cr; aIm[b * Nn_] = ci;
    for (int i = 1; i < Nn_; i++) {
      const float r = 1.0f / (cr * cr + ci * ci);
      const float dre = Vb[i] + 2.0f, dim = -gb[i];
      const float ncr = dre - cr * r;
      const float nci = dim + ci * r;
      cr = ncr; ci = nci;
      aRe[b * Nn_ + i] = cr; aIm[b * Nn_ + i] = ci;
    }
  } else {
    float cr = Vb[Nn_ - 1] + 2.0f, ci = -gb[Nn_ - 1];
    bRe[b * Nn_ + Nn_ - 1] = cr; bIm[b * Nn_ + Nn_ - 1] = ci;
    for (int i = Nn_ - 2; i >= 0; i--) {
      const float r = 1.0f / (cr * cr + ci * ci);
      const float dre = Vb[i] + 2.0f, dim = -gb[i];
      const float ncr = dre - cr * r;
      const float nci = dim + ci * r;
      cr = ncr; ci = nci;
      bRe[b * Nn_ + i] = cr; bIm[b * Nn_ + i] = ci;
    }
  }
}

// ---------- x1 = x + [G.re,G.im] @ w_bk + b_bk ----------
__global__ __launch_bounds__(256) void k_bk_add(
    const float* __restrict__ x, const float* __restrict__ aRe, const float* __restrict__ aIm,
    const float* __restrict__ bRe, const float* __restrict__ bIm,
    const float* __restrict__ V, const float* __restrict__ gam,
    const float* __restrict__ w_bk, const float* __restrict__ b_bk, float* __restrict__ x1) {
  const int m = blockIdx.x, t = threadIdx.x;
  const float dre = V[m] + 2.0f, dim = -gam[m];
  const float nr = aRe[m] + bRe[m] - dre;
  const float ni = aIm[m] + bIm[m] - dim;
  const float r = 1.0f / (nr * nr + ni * ni);
  const float Gre = nr * r, Gim = -ni * r;
  const float4 xv = ((const float4*)(x + (size_t)m * Dd))[t];
  const float4 w0 = ((const float4*)w_bk)[t];
  const float4 w1 = ((const float4*)(w_bk + Dd))[t];
  const float4 bb = ((const float4*)b_bk)[t];
  float4 o;
  o.x = xv.x + Gre * w0.x + Gim * w1.x + bb.x;
  o.y = xv.y + Gre * w0.y + Gim * w1.y + bb.y;
  o.z = xv.z + Gre * w0.z + Gim * w1.z + bb.z;
  o.w = xv.w + Gre * w0.w + Gim * w1.w + bb.w;
  ((float4*)(x1 + (size_t)m * Dd))[t] = o;
}

// ---------- generic layernorm ----------
__global__ __launch_bounds__(256) void k_ln(
    const float* __restrict__ x, const float* __restrict__ g, const float* __restrict__ bt,
    float* __restrict__ y) {
  __shared__ float sc[8];
  const int m = blockIdx.x, t = threadIdx.x;
  const float4 xv = ((const float4*)(x + (size_t)m * Dd))[t];
  float s = xv.x + xv.y + xv.z + xv.w;
  float ss = fmaf(xv.x, xv.x, fmaf(xv.y, xv.y, fmaf(xv.z, xv.z, xv.w * xv.w)));
  block_reduce2(s, ss, sc);
  const float mean = s * (1.0f / Dd);
  const float var = ss * (1.0f / Dd) - mean * mean;
  const float rs = rsqrtf(var + 1e-5f);
  const float4 gv = ((const float4*)g)[t];
  const float4 bv = ((const float4*)bt)[t];
  float4 o;
  o.x = (xv.x - mean) * rs * gv.x + bv.x;
  o.y = (xv.y - mean) * rs * gv.y + bv.y;
  o.z = (xv.z - mean) * rs * gv.z + bv.z;
  o.w = (xv.w - mean) * rs * gv.w + bv.w;
  ((float4*)(y + (size_t)m * Dd))[t] = o;
}

// ---------- generic fp32 GEMM: C = A(MxK) @ W(KxN) + bias (+gelu) (+res) ----------
__global__ __launch_bounds__(256) void k_gemm(
    const float* __restrict__ A, const float* __restrict__ W,
    const float* __restrict__ bias, const float* __restrict__ res,
    float* __restrict__ Cc, int M, int K, int Nc, int flags) {
  __shared__ float Ast[16][132];
  __shared__ float Ws[16][68];
  const int t = threadIdx.x;
  const int n0 = blockIdx.x * 64;
  const int m0 = blockIdx.y * 128;
  const int tx = t & 15, ty = t >> 4;
  float acc[8][4];
#pragma unroll
  for (int i = 0; i < 8; i++)
#pragma unroll
    for (int j = 0; j < 4; j++) acc[i][j] = 0.0f;

  for (int kt = 0; kt < K; kt += 16) {
#pragma unroll
    for (int l = 0; l < 2; l++) {
      const int fi = t + 256 * l;
      const int r = fi >> 2, cc = (fi & 3) << 2;
      const float4 av = *(const float4*)(A + (size_t)(m0 + r) * K + kt + cc);
      Ast[cc + 0][r] = av.x; Ast[cc + 1][r] = av.y;
      Ast[cc + 2][r] = av.z; Ast[cc + 3][r] = av.w;
    }
    {
      const int r = t >> 4, cc = (t & 15) << 2;
      *(float4*)&Ws[r][cc] = *(const float4*)(W + (size_t)(kt + r) * Nc + n0 + cc);
    }
    __syncthreads();
#pragma unroll
    for (int k = 0; k < 16; k++) {
      const float4 a0 = *(const float4*)&Ast[k][ty * 8];
      const float4 a1 = *(const float4*)&Ast[k][ty * 8 + 4];
      const float4 w0 = *(const float4*)&Ws[k][tx * 4];
      const float aa[8] = {a0.x, a0.y, a0.z, a0.w, a1.x, a1.y, a1.z, a1.w};
      const float ww[4] = {w0.x, w0.y, w0.z, w0.w};
#pragma unroll
      for (int i = 0; i < 8; i++)
#pragma unroll
        for (int j = 0; j < 4; j++) acc[i][j] = fmaf(aa[i], ww[j], acc[i][j]);
    }
    __syncthreads();
  }
  const float4 bv = *(const float4*)(bias + n0 + tx * 4);
#pragma unroll
  for (int i = 0; i < 8; i++) {
    const size_t row = (size_t)m0 + ty * 8 + i;
    float4 o;
    o.x = acc[i][0] + bv.x; o.y = acc[i][1] + bv.y;
    o.z = acc[i][2] + bv.z; o.w = acc[i][3] + bv.w;
    if (flags & 1) { o.x = gelu_f(o.x); o.y = gelu_f(o.y); o.z = gelu_f(o.z); o.w = gelu_f(o.w); }
    if (flags & 2) {
      const float4 rv = *(const float4*)(res + row * Nc + n0 + tx * 4);
      o.x += rv.x; o.y += rv.y; o.z += rv.z; o.w += rv.w;
    }
    *(float4*)(Cc + row * Nc + n0 + tx * 4) = o;
  }
}

// ---------- Hebbian phase A: per-chunk decayed outer-product sums ----------
__global__ __launch_bounds__(256) void k_heb_chunk(
    const float* __restrict__ qkv, const float* __restrict__ gam,
    float* __restrict__ U, float* __restrict__ Dc) {
  __shared__ float kw[4096];
  __shared__ float vS[4096];
  __shared__ float cum[64];
  const int bx = blockIdx.x;
  const int c = bx & 31, bh = bx >> 5, b = bh >> 3, h = bh & 7;
  const int t = threadIdx.x;
  const int n0 = c * 64;
  const size_t base = ((size_t)(b * Nn_ + n0)) * 1536 + h * 64;
#pragma unroll
  for (int l = 0; l < 16; l++) {
    const int idx = t + 256 * l;
    const int s = idx >> 6, d = idx & 63;
    const size_t gi = base + (size_t)s * 1536 + d;
    kw[idx] = qkv[gi + 512];
    vS[idx] = qkv[gi + 1024];
  }
  if (t < 64) {
    float val = 0.01f * gam[b * Nn_ + n0 + t];
#pragma unroll
    for (int off = 1; off < 64; off <<= 1) {
      const float o = __shfl_up(val, off, 64);
      if (t >= off) val += o;
    }
    cum[t] = val;
  }
  __syncthreads();
  const float total = cum[63];
#pragma unroll
  for (int l = 0; l < 16; l++) {
    const int idx = t + 256 * l;
    const int s = idx >> 6;
    kw[idx] *= 0.1f * __expf(cum[s] - total);
  }
  __syncthreads();
  const int td = (t & 15) << 2, te = (t >> 4) << 2;
  float acc[4][4];
#pragma unroll
  for (int i = 0; i < 4; i++)
#pragma unroll
    for (int j = 0; j < 4; j++) acc[i][j] = 0.0f;
  for (int s = 0; s < 64; s++) {
    const float4 kk = *(const float4*)&kw[s * 64 + td];
    const float4 vv = *(const float4*)&vS[s * 64 + te];
    const float ka[4] = {kk.x, kk.y, kk.z, kk.w};
    const float va[4] = {vv.x, vv.y, vv.z, vv.w};
#pragma unroll
    for (int i = 0; i < 4; i++)
#pragma unroll
      for (int j = 0; j < 4; j++) acc[i][j] = fmaf(ka[i], va[j], acc[i][j]);
  }
  float* Up = U + (size_t)bx * 4096;
#pragma unroll
  for (int i = 0; i < 4; i++)
#pragma unroll
    for (int j = 0; j < 4; j++) Up[(td + i) * 64 + te + j] = acc[i][j];
  if (t == 0) Dc[bx] = __expf(-total);
}

// ---------- Hebbian phase B: carry W across chunks; store W_in per chunk ----------
__global__ __launch_bounds__(256) void k_heb_scan(
    const float* __restrict__ U, const float* __restrict__ Dc, float* __restrict__ Win) {
  const int bh = blockIdx.x, t = threadIdx.x;
  float wreg[16];
#pragma unroll
  for (int j = 0; j < 16; j++) wreg[j] = 0.0f;
  for (int c = 0; c < 32; c++) {
    const size_t basei = ((size_t)bh * 32 + c) * 4096;
    const float dcv = Dc[bh * 32 + c];
#pragma unroll
    for (int j = 0; j < 16; j++) {
      Win[basei + t + 256 * j] = wreg[j];
      wreg[j] = dcv * wreg[j] + U[basei + t + 256 * j];
    }
  }
}

// ---------- Hebbian phase C: intra-chunk causal attn + inter-chunk q@W_in ----------
__global__ __launch_bounds__(256) void k_heb_out(
    const float* __restrict__ qkv, const float* __restrict__ gam,
    const float* __restrict__ Win, float* __restrict__ heb) {
  __shared__ float qS[4096];
  __shared__ float kT[4096];  // k transposed; later reused for Win
  __shared__ float vS[4096];
  __shared__ float P[4096];   // first 64 floats temporarily hold cum
  const int bx = blockIdx.x;
  const int c = bx & 31, bh = bx >> 5, b = bh >> 3, h = bh & 7;
  const int t = threadIdx.x;
  const int n0 = c * 64;
  const size_t base = ((size_t)(b * Nn_ + n0)) * 1536 + h * 64;
#pragma unroll
  for (int l = 0; l < 16; l++) {
    const int idx = t + 256 * l;
    const int s = idx >> 6, d = idx & 63;
    const size_t gi = base + (size_t)s * 1536 + d;
    qS[idx] = qkv[gi];
    kT[d * 64 + s] = qkv[gi + 512];
    vS[idx] = qkv[gi + 1024];
  }
  if (t < 64) {
    float val = 0.01f * gam[b * Nn_ + n0 + t];
#pragma unroll
    for (int off = 1; off < 64; off <<= 1) {
      const float o = __shfl_up(val, off, 64);
      if (t >= off) val += o;
    }
    P[t] = val;
  }
  __syncthreads();
  const int tr = (t >> 4) << 2;  // time-row group
  const int tc = (t & 15) << 2;  // col group (ss for P, e for output)
  float er[4], es[4];
#pragma unroll
  for (int r = 0; r < 4; r++) er[r] = __expf(-P[tr + r]);
#pragma unroll
  for (int j = 0; j < 4; j++) es[j] = 0.1f * __expf(P[tc + j]);
  __syncthreads();  // everyone has cum in regs; P may now be overwritten
  float acc[4][4];
#pragma unroll
  for (int i = 0; i < 4; i++)
#pragma unroll
    for (int j = 0; j < 4; j++) acc[i][j] = 0.0f;
  for (int d = 0; d < 64; d++) {
    const float4 kk = *(const float4*)&kT[d * 64 + tc];
    const float ka[4] = {kk.x, kk.y, kk.z, kk.w};
#pragma unroll
    for (int r = 0; r < 4; r++) {
      const float qv = qS[(tr + r) * 64 + d];
#pragma unroll
      for (int j = 0; j < 4; j++) acc[r][j] = fmaf(qv, ka[j], acc[r][j]);
    }
  }
#pragma unroll
  for (int r = 0; r < 4; r++)
#pragma unroll
    for (int j = 0; j < 4; j++) {
      const int tt = tr + r, ssi = tc + j;
      const float wgt = (ssi <= tt) ? er[r] * es[j] : 0.0f;
      P[tt * 64 + ssi] = acc[r][j] * wgt;
    }
  __syncthreads();
  const size_t wb = (size_t)bx * 4096;
#pragma unroll
  for (int l = 0; l < 16; l++) {
    const int idx = t + 256 * l;
    kT[idx] = Win[wb + idx];
  }
  __syncthreads();
  float o1[4][4], o2[4][4];
#pragma unroll
  for (int i = 0; i < 4; i++)
#pragma unroll
    for (int j = 0; j < 4; j++) { o1[i][j] = 0.0f; o2[i][j] = 0.0f; }
  for (int s = 0; s < 64; s++) {
    const float4 vv = *(const float4*)&vS[s * 64 + tc];
    const float4 ww = *(const float4*)&kT[s * 64 + tc];
    const float va[4] = {vv.x, vv.y, vv.z, vv.w};
    const float wa[4] = {ww.x, ww.y, ww.z, ww.w};
#pragma unroll
    for (int r = 0; r < 4; r++) {
      const float pv = P[(tr + r) * 64 + s];
      const float qv = qS[(tr + r) * 64 + s];
#pragma unroll
      for (int j = 0; j < 4; j++) {
        o1[r][j] = fmaf(pv, va[j], o1[r][j]);
        o2[r][j] = fmaf(qv, wa[j], o2[r][j]);
      }
    }
  }
#pragma unroll
  for (int r = 0; r < 4; r++) {
    const int n = n0 + tr + r;
    float4 o;
    o.x = o1[r][0] + er[r] * o2[r][0];
    o.y = o1[r][1] + er[r] * o2[r][1];
    o.z = o1[r][2] + er[r] * o2[r][2];
    o.w = o1[r][3] + er[r] * o2[r][3];
    *(float4*)&heb[((size_t)b * Nn_ + n) * 512 + h * 64 + tc] = o;
  }
}

extern "C" void kernel_launch(void* const* d_in, const int* in_sizes, int n_in,
                              void* d_out, int out_size, void* d_ws, size_t ws_size,
                              hipStream_t stream) {
  const float* x     = (const float*)d_in[0];
  const float* ln1g  = (const float*)d_in[1];
  const float* ln1b  = (const float*)d_in[2];
  const float* ln2g  = (const float*)d_in[3];
  const float* ln2b  = (const float*)d_in[4];
  const float* ln3g  = (const float*)d_in[5];
  const float* ln3b  = (const float*)d_in[6];
  const float* w_pot = (const float*)d_in[7];
  const float* b_pot = (const float*)d_in[8];
  const float* w_bk  = (const float*)d_in[9];
  const float* b_bk  = (const float*)d_in[10];
  const float* w_qkv = (const float*)d_in[11];
  const float* b_qkv = (const float*)d_in[12];
  const float* w_out = (const float*)d_in[13];
  const float* b_out = (const float*)d_in[14];
  const float* w_ff1 = (const float*)d_in[15];
  const float* b_ff1 = (const float*)d_in[16];
  const float* w_ff2 = (const float*)d_in[17];
  const float* b_ff2 = (const float*)d_in[18];
  float* out = (float*)d_out;
  float* ws = (float*)d_ws;

  // workspace layout (floats)
  float* V    = ws;                   // 8192
  float* gam  = ws + 8192;            // 8192
  float* aRe  = ws + 16384;
  float* aIm  = ws + 24576;
  float* bRe  = ws + 32768;
  float* bIm  = ws + 40960;
  float* Dc   = ws + 49152;           // 1024
  float* x1   = ws + 65536;           // 8.39M  (later: ff hidden slab buffer)
  float* xn   = x1 + 8388608;         // 8.39M  (xn2, later xn3)
  float* qkvb = xn + 8388608;         // 12.58M (later: x2)
  float* Ub   = qkvb + 12582912;      // 4.19M  (later: heb)
  float* Win  = Ub + 4194304;         // 4.19M
  float* hebb = Ub;
  float* x2   = qkvb;
  float* hbuf = x1;

  k_ln_pot<<<Tt, 256, 0, stream>>>(x, ln1g, ln1b, w_pot, b_pot, V, gam);
  k_cf<<<8, 64, 0, stream>>>(V, gam, aRe, aIm, bRe, bIm);
  k_bk_add<<<Tt, 256, 0, stream>>>(x, aRe, aIm, bRe, bIm, V, gam, w_bk, b_bk, x1);
  k_ln<<<Tt, 256, 0, stream>>>(x1, ln2g, ln2b, xn);
  k_gemm<<<dim3(1536 / 64, 8192 / 128), 256, 0, stream>>>(xn, w_qkv, b_qkv, nullptr, qkvb,
                                                          8192, 1024, 1536, 0);
  k_heb_chunk<<<1024, 256, 0, stream>>>(qkvb, gam, Ub, Dc);
  k_heb_scan<<<32, 256, 0, stream>>>(Ub, Dc, Win);
  k_heb_out<<<1024, 256, 0, stream>>>(qkvb, gam, Win, hebb);
  k_gemm<<<dim3(1024 / 64, 8192 / 128), 256, 0, stream>>>(hebb, w_out, b_out, x1, x2,
                                                          8192, 512, 1024, 2);
  k_ln<<<Tt, 256, 0, stream>>>(x2, ln3g, ln3b, xn);
  for (int sl = 0; sl < 4; sl++) {
    const size_t off = (size_t)sl * 2048 * 1024;
    k_gemm<<<dim3(4096 / 64, 2048 / 128), 256, 0, stream>>>(xn + off, w_ff1, b_ff1, nullptr,
                                                            hbuf, 2048, 1024, 4096, 1);
    k_gemm<<<dim3(1024 / 64, 2048 / 128), 256, 0, stream>>>(hbuf, w_ff2, b_ff2, x2 + off,
                                                            out + off, 2048, 4096, 1024, 2);
  }
}

// Round 2
// 1063.818 us; speedup vs baseline: 3.2816x; 3.2816x over previous
//
#include <hip/hip_runtime.h>

#define Bn 4
#define Nn_ 2048
#define Dd 1024
#define Hh 8
#define HDd 64
#define Tt 8192   // Bn*Nn_

typedef short s16x8 __attribute__((ext_vector_type(8)));
typedef float f32x4 __attribute__((ext_vector_type(4)));

__device__ __forceinline__ unsigned short f2bf(float f) {
  unsigned u = __float_as_uint(f);
  return (unsigned short)((u + 0x7fffu + ((u >> 16) & 1u)) >> 16);
}

__device__ __forceinline__ void bf8_to_f(const unsigned short* p, float* o) {
  const uint4 u = *(const uint4*)p;
  o[0] = __uint_as_float(u.x << 16);
  o[1] = __uint_as_float(u.x & 0xffff0000u);
  o[2] = __uint_as_float(u.y << 16);
  o[3] = __uint_as_float(u.y & 0xffff0000u);
  o[4] = __uint_as_float(u.z << 16);
  o[5] = __uint_as_float(u.z & 0xffff0000u);
  o[6] = __uint_as_float(u.w << 16);
  o[7] = __uint_as_float(u.w & 0xffff0000u);
}

__device__ __forceinline__ void gld16(const void* g, void* l) {
  __builtin_amdgcn_global_load_lds(
      (const __attribute__((address_space(1))) unsigned int*)(uintptr_t)g,
      (__attribute__((address_space(3))) unsigned int*)(uintptr_t)l, 16, 0, 0);
}

__device__ __forceinline__ void block_reduce2(float& a, float& b, float* sc) {
#pragma unroll
  for (int off = 32; off > 0; off >>= 1) {
    a += __shfl_down(a, off, 64);
    b += __shfl_down(b, off, 64);
  }
  __syncthreads();
  if ((threadIdx.x & 63) == 0) { int wid = threadIdx.x >> 6; sc[wid] = a; sc[4 + wid] = b; }
  __syncthreads();
  a = sc[0] + sc[1] + sc[2] + sc[3];
  b = sc[4] + sc[5] + sc[6] + sc[7];
}

__device__ __forceinline__ float gelu_f(float u) {
  const float c = 0.7978845608028654f * (u + 0.044715f * u * u * u);
  const float e = __expf(2.0f * c);
  const float th = 1.0f - 2.0f / (1.0f + e);
  return 0.5f * u * (1.0f + th);
}

// ---------- weight convert+transpose: W (KxN f32) -> WT (NxK bf16) ----------
__global__ __launch_bounds__(256) void k_wt(const float* __restrict__ W,
                                            unsigned short* __restrict__ WT, int K, int N) {
  __shared__ float tile[32][33];
  const int n0 = blockIdx.x * 32, k0 = blockIdx.y * 32;
  const int tx = threadIdx.x & 31, ty = threadIdx.x >> 5;  // ty 0..7
#pragma unroll
  for (int i = 0; i < 4; i++) {
    const int kk = ty + i * 8;
    tile[kk][tx] = W[(size_t)(k0 + kk) * N + n0 + tx];
  }
  __syncthreads();
#pragma unroll
  for (int i = 0; i < 4; i++) {
    const int nn = ty + i * 8;
    WT[(size_t)(n0 + nn) * K + k0 + tx] = f2bf(tile[tx][nn]);
  }
}

// ---------- LN1 + potential projection (V, gamma) ----------
__global__ __launch_bounds__(256) void k_ln_pot(
    const float* __restrict__ x, const float* __restrict__ g, const float* __restrict__ bt,
    const float* __restrict__ w_pot, const float* __restrict__ b_pot,
    float* __restrict__ V, float* __restrict__ gam) {
  __shared__ float sc[8];
  const int m = blockIdx.x, t = threadIdx.x;
  const float4 xv = ((const float4*)(x + (size_t)m * Dd))[t];
  float s = xv.x + xv.y + xv.z + xv.w;
  float ss = fmaf(xv.x, xv.x, fmaf(xv.y, xv.y, fmaf(xv.z, xv.z, xv.w * xv.w)));
  block_reduce2(s, ss, sc);
  const float mean = s * (1.0f / Dd);
  const float var = ss * (1.0f / Dd) - mean * mean;
  const float rs = rsqrtf(var + 1e-5f);
  const float4 gv = ((const float4*)g)[t];
  const float4 bv = ((const float4*)bt)[t];
  const float xn0 = (xv.x - mean) * rs * gv.x + bv.x;
  const float xn1 = (xv.y - mean) * rs * gv.y + bv.y;
  const float xn2 = (xv.z - mean) * rs * gv.z + bv.z;
  const float xn3 = (xv.w - mean) * rs * gv.w + bv.w;
  const float4 wp0 = ((const float4*)w_pot)[t * 2];
  const float4 wp1 = ((const float4*)w_pot)[t * 2 + 1];
  float s0 = xn0 * wp0.x + xn1 * wp0.z + xn2 * wp1.x + xn3 * wp1.z;
  float s1 = xn0 * wp0.y + xn1 * wp0.w + xn2 * wp1.y + xn3 * wp1.w;
  block_reduce2(s0, s1, sc);
  if (t == 0) {
    V[m] = s0 + b_pot[0];
    const float p1 = s1 + b_pot[1];
    const float sp = fmaxf(p1, 0.0f) + log1pf(expf(-fabsf(p1)));
    gam[m] = sp + 0.1f;
  }
}

// ---------- continued fraction scans (serial; 8 independent chains) ----------
__global__ void k_cf(const float* __restrict__ V, const float* __restrict__ gam,
                     float* __restrict__ aRe, float* __restrict__ aIm,
                     float* __restrict__ bRe, float* __restrict__ bIm) {
  if (threadIdx.x != 0) return;
  const int b = blockIdx.x >> 1, dir = blockIdx.x & 1;
  const float* Vb = V + b * Nn_;
  const float* gb = gam + b * Nn_;
  if (dir == 0) {
    float cr = Vb[0] + 2.0f, ci = -gb[0];
    aRe[b * Nn_] = cr; aIm[b * Nn_] = ci;
    for (int i = 1; i < Nn_; i++) {
      const float r = 1.0f / (cr * cr + ci * ci);
      cr = Vb[i] + 2.0f - cr * r;
      ci = -gb[i] + ci * r;
      aRe[b * Nn_ + i] = cr; aIm[b * Nn_ + i] = ci;
    }
  } else {
    float cr = Vb[Nn_ - 1] + 2.0f, ci = -gb[Nn_ - 1];
    bRe[b * Nn_ + Nn_ - 1] = cr; bIm[b * Nn_ + Nn_ - 1] = ci;
    for (int i = Nn_ - 2; i >= 0; i--) {
      const float r = 1.0f / (cr * cr + ci * ci);
      cr = Vb[i] + 2.0f - cr * r;
      ci = -gb[i] + ci * r;
      bRe[b * Nn_ + i] = cr; bIm[b * Nn_ + i] = ci;
    }
  }
}

// ---------- x1 = x + [G.re,G.im] @ w_bk + b_bk ----------
__global__ __launch_bounds__(256) void k_bk_add(
    const float* __restrict__ x, const float* __restrict__ aRe, const float* __restrict__ aIm,
    const float* __restrict__ bRe, const float* __restrict__ bIm,
    const float* __restrict__ V, const float* __restrict__ gam,
    const float* __restrict__ w_bk, const float* __restrict__ b_bk, float* __restrict__ x1) {
  const int m = blockIdx.x, t = threadIdx.x;
  const float dre = V[m] + 2.0f, dim = -gam[m];
  const float nr = aRe[m] + bRe[m] - dre;
  const float ni = aIm[m] + bIm[m] - dim;
  const float r = 1.0f / (nr * nr + ni * ni);
  const float Gre = nr * r, Gim = -ni * r;
  const float4 xv = ((const float4*)(x + (size_t)m * Dd))[t];
  const float4 w0 = ((const float4*)w_bk)[t];
  const float4 w1 = ((const float4*)(w_bk + Dd))[t];
  const float4 bb = ((const float4*)b_bk)[t];
  float4 o;
  o.x = xv.x + Gre * w0.x + Gim * w1.x + bb.x;
  o.y = xv.y + Gre * w0.y + Gim * w1.y + bb.y;
  o.z = xv.z + Gre * w0.z + Gim * w1.z + bb.z;
  o.w = xv.w + Gre * w0.w + Gim * w1.w + bb.w;
  ((float4*)(x1 + (size_t)m * Dd))[t] = o;
}

// ---------- layernorm -> bf16 output ----------
__global__ __launch_bounds__(256) void k_ln_bf(
    const float* __restrict__ x, const float* __restrict__ g, const float* __restrict__ bt,
    unsigned short* __restrict__ y) {
  __shared__ float sc[8];
  const int m = blockIdx.x, t = threadIdx.x;
  const float4 xv = ((const float4*)(x + (size_t)m * Dd))[t];
  float s = xv.x + xv.y + xv.z + xv.w;
  float ss = fmaf(xv.x, xv.x, fmaf(xv.y, xv.y, fmaf(xv.z, xv.z, xv.w * xv.w)));
  block_reduce2(s, ss, sc);
  const float mean = s * (1.0f / Dd);
  const float var = ss * (1.0f / Dd) - mean * mean;
  const float rs = rsqrtf(var + 1e-5f);
  const float4 gv = ((const float4*)g)[t];
  const float4 bv = ((const float4*)bt)[t];
  ushort4 pk;
  pk.x = f2bf((xv.x - mean) * rs * gv.x + bv.x);
  pk.y = f2bf((xv.y - mean) * rs * gv.y + bv.y);
  pk.z = f2bf((xv.z - mean) * rs * gv.z + bv.z);
  pk.w = f2bf((xv.w - mean) * rs * gv.w + bv.w);
  ((ushort4*)(y + (size_t)m * Dd))[t] = pk;
}

// ---------- bf16 MFMA GEMM: C = A(MxK) @ BT(NxK)^T + bias; epilogue flags ----------
// flags: 1=gelu, 2=add fp32 res, 4=store bf16 (else fp32)
__global__ __launch_bounds__(256) void k_gemm_bf(
    const unsigned short* __restrict__ A, const unsigned short* __restrict__ BT,
    const float* __restrict__ bias, const float* __restrict__ res,
    void* __restrict__ C, int M, int K, int N, int flags) {
  __shared__ unsigned short As[128 * 32];
  __shared__ unsigned short Bs[128 * 32];
  const int t = threadIdx.x;
  const int n0 = blockIdx.x * 128;
  const int m0 = blockIdx.y * 128;
  const int lane = t & 63;
  const int w = t >> 6;
  const int wr = (w >> 1) * 64, wc = (w & 1) * 64;
  const int mrow = lane & 15;
  const int kq = (lane >> 4) * 8;

  f32x4 acc[4][4];
#pragma unroll
  for (int i = 0; i < 4; i++)
#pragma unroll
    for (int j = 0; j < 4; j++) acc[i][j] = (f32x4){0.f, 0.f, 0.f, 0.f};

  for (int kt = 0; kt < K; kt += 32) {
#pragma unroll
    for (int l = 0; l < 2; l++) {
      const int idx = t + 256 * l;       // 0..511, 8 bf16 each
      const int row = idx >> 2;
      const int col = (idx & 3) * 8;
      gld16(A + (size_t)(m0 + row) * K + kt + col, As + idx * 8);
      gld16(BT + (size_t)(n0 + row) * K + kt + col, Bs + idx * 8);
    }
    __syncthreads();
    s16x8 aF[4], bF[4];
#pragma unroll
    for (int i = 0; i < 4; i++) {
      aF[i] = *(const s16x8*)(As + (wr + i * 16 + mrow) * 32 + kq);
      bF[i] = *(const s16x8*)(Bs + (wc + i * 16 + mrow) * 32 + kq);
    }
#pragma unroll
    for (int i = 0; i < 4; i++)
#pragma unroll
      for (int j = 0; j < 4; j++)
        acc[i][j] = __builtin_amdgcn_mfma_f32_16x16x32_bf16(aF[i], bF[j], acc[i][j], 0, 0, 0);
    __syncthreads();
  }

  float bsv[4];
#pragma unroll
  for (int j = 0; j < 4; j++) bsv[j] = bias[n0 + wc + j * 16 + (lane & 15)];
  const int r0 = m0 + wr + (lane >> 4) * 4;
#pragma unroll
  for (int i = 0; i < 4; i++) {
#pragma unroll
    for (int rg = 0; rg < 4; rg++) {
      const size_t row = (size_t)(r0 + i * 16 + rg);
#pragma unroll
      for (int j = 0; j < 4; j++) {
        const int col = n0 + wc + j * 16 + (lane & 15);
        float v = acc[i][j][rg] + bsv[j];
        if (flags & 1) v = gelu_f(v);
        if (flags & 2) v += res[row * N + col];
        if (flags & 4) ((unsigned short*)C)[row * N + col] = f2bf(v);
        else ((float*)C)[row * N + col] = v;
      }
    }
  }
}

// ---------- Hebbian phase A: per-chunk decayed outer-product sums ----------
__global__ __launch_bounds__(256) void k_heb_chunk(
    const unsigned short* __restrict__ qkv, const float* __restrict__ gam,
    float* __restrict__ U, float* __restrict__ Dc) {
  __shared__ float kw[4096];
  __shared__ float vS[4096];
  __shared__ float cum[64];
  const int bx = blockIdx.x;
  const int c = bx & 31, bh = bx >> 5, b = bh >> 3, h = bh & 7;
  const int t = threadIdx.x;
  const int n0 = c * 64;
  const size_t base = ((size_t)(b * Nn_ + n0)) * 1536 + h * 64;
#pragma unroll
  for (int l = 0; l < 2; l++) {
    const int idx8 = t + 256 * l;       // 0..511
    const int s = idx8 >> 3;
    const int d0 = (idx8 & 7) << 3;
    const size_t gi = base + (size_t)s * 1536 + d0;
    bf8_to_f(qkv + gi + 512, &kw[s * 64 + d0]);
    bf8_to_f(qkv + gi + 1024, &vS[s * 64 + d0]);
  }
  if (t < 64) {
    float val = 0.01f * gam[b * Nn_ + n0 + t];
#pragma unroll
    for (int off = 1; off < 64; off <<= 1) {
      const float o = __shfl_up(val, off, 64);
      if (t >= off) val += o;
    }
    cum[t] = val;
  }
  __syncthreads();
  const float total = cum[63];
#pragma unroll
  for (int l = 0; l < 16; l++) {
    const int idx = t + 256 * l;
    const int s = idx >> 6;
    kw[idx] *= 0.1f * __expf(cum[s] - total);
  }
  __syncthreads();
  const int td = (t & 15) << 2, te = (t >> 4) << 2;
  float acc[4][4];
#pragma unroll
  for (int i = 0; i < 4; i++)
#pragma unroll
    for (int j = 0; j < 4; j++) acc[i][j] = 0.0f;
  for (int s = 0; s < 64; s++) {
    const float4 kk = *(const float4*)&kw[s * 64 + td];
    const float4 vv = *(const float4*)&vS[s * 64 + te];
    const float ka[4] = {kk.x, kk.y, kk.z, kk.w};
    const float va[4] = {vv.x, vv.y, vv.z, vv.w};
#pragma unroll
    for (int i = 0; i < 4; i++)
#pragma unroll
      for (int j = 0; j < 4; j++) acc[i][j] = fmaf(ka[i], va[j], acc[i][j]);
  }
  float* Up = U + (size_t)bx * 4096;
#pragma unroll
  for (int i = 0; i < 4; i++)
#pragma unroll
    for (int j = 0; j < 4; j++) Up[(td + i) * 64 + te + j] = acc[i][j];
  if (t == 0) Dc[bx] = __expf(-total);
}

// ---------- Hebbian phase B: carry W across chunks ----------
__global__ __launch_bounds__(256) void k_heb_scan(
    const float* __restrict__ U, const float* __restrict__ Dc, float* __restrict__ Win) {
  const int bh = blockIdx.x, t = threadIdx.x;
  float wreg[16];
#pragma unroll
  for (int j = 0; j < 16; j++) wreg[j] = 0.0f;
  for (int c = 0; c < 32; c++) {
    const size_t basei = ((size_t)bh * 32 + c) * 4096;
    const float dcv = Dc[bh * 32 + c];
#pragma unroll
    for (int j = 0; j < 16; j++) {
      Win[basei + t + 256 * j] = wreg[j];
      wreg[j] = dcv * wreg[j] + U[basei + t + 256 * j];
    }
  }
}

// ---------- Hebbian phase C: intra-chunk causal + inter-chunk q@W_in ----------
__global__ __launch_bounds__(256) void k_heb_out(
    const unsigned short* __restrict__ qkv, const float* __restrict__ gam,
    const float* __restrict__ Win, unsigned short* __restrict__ heb) {
  __shared__ float qS[4096];
  __shared__ float kT[4096];
  __shared__ float vS[4096];
  __shared__ float P[4096];
  const int bx = blockIdx.x;
  const int c = bx & 31, bh = bx >> 5, b = bh >> 3, h = bh & 7;
  const int t = threadIdx.x;
  const int n0 = c * 64;
  const size_t base = ((size_t)(b * Nn_ + n0)) * 1536 + h * 64;
#pragma unroll
  for (int l = 0; l < 2; l++) {
    const int idx8 = t + 256 * l;
    const int s = idx8 >> 3;
    const int d0 = (idx8 & 7) << 3;
    const size_t gi = base + (size_t)s * 1536 + d0;
    bf8_to_f(qkv + gi, &qS[s * 64 + d0]);
    bf8_to_f(qkv + gi + 1024, &vS[s * 64 + d0]);
    float tmp[8];
    bf8_to_f(qkv + gi + 512, tmp);
#pragma unroll
    for (int j = 0; j < 8; j++) kT[(d0 + j) * 64 + s] = tmp[j];
  }
  if (t < 64) {
    float val = 0.01f * gam[b * Nn_ + n0 + t];
#pragma unroll
    for (int off = 1; off < 64; off <<= 1) {
      const float o = __shfl_up(val, off, 64);
      if (t >= off) val += o;
    }
    P[t] = val;
  }
  __syncthreads();
  const int tr = (t >> 4) << 2;
  const int tc = (t & 15) << 2;
  float er[4], es[4];
#pragma unroll
  for (int r = 0; r < 4; r++) er[r] = __expf(-P[tr + r]);
#pragma unroll
  for (int j = 0; j < 4; j++) es[j] = 0.1f * __expf(P[tc + j]);
  __syncthreads();
  float acc[4][4];
#pragma unroll
  for (int i = 0; i < 4; i++)
#pragma unroll
    for (int j = 0; j < 4; j++) acc[i][j] = 0.0f;
  for (int d = 0; d < 64; d++) {
    const float4 kk = *(const float4*)&kT[d * 64 + tc];
    const float ka[4] = {kk.x, kk.y, kk.z, kk.w};
#pragma unroll
    for (int r = 0; r < 4; r++) {
      const float qv = qS[(tr + r) * 64 + d];
#pragma unroll
      for (int j = 0; j < 4; j++) acc[r][j] = fmaf(qv, ka[j], acc[r][j]);
    }
  }
#pragma unroll
  for (int r = 0; r < 4; r++)
#pragma unroll
    for (int j = 0; j < 4; j++) {
      const int tt = tr + r, ssi = tc + j;
      const float wgt = (ssi <= tt) ? er[r] * es[j] : 0.0f;
      P[tt * 64 + ssi] = acc[r][j] * wgt;
    }
  __syncthreads();
  const size_t wb = (size_t)bx * 4096;
#pragma unroll
  for (int l = 0; l < 16; l++) {
    const int idx = t + 256 * l;
    kT[idx] = Win[wb + idx];
  }
  __syncthreads();
  float o1[4][4], o2[4][4];
#pragma unroll
  for (int i = 0; i < 4; i++)
#pragma unroll
    for (int j = 0; j < 4; j++) { o1[i][j] = 0.0f; o2[i][j] = 0.0f; }
  for (int s = 0; s < 64; s++) {
    const float4 vv = *(const float4*)&vS[s * 64 + tc];
    const float4 ww = *(const float4*)&kT[s * 64 + tc];
    const float va[4] = {vv.x, vv.y, vv.z, vv.w};
    const float wa[4] = {ww.x, ww.y, ww.z, ww.w};
#pragma unroll
    for (int r = 0; r < 4; r++) {
      const float pv = P[(tr + r) * 64 + s];
      const float qv = qS[(tr + r) * 64 + s];
#pragma unroll
      for (int j = 0; j < 4; j++) {
        o1[r][j] = fmaf(pv, va[j], o1[r][j]);
        o2[r][j] = fmaf(qv, wa[j], o2[r][j]);
      }
    }
  }
#pragma unroll
  for (int r = 0; r < 4; r++) {
    const int n = n0 + tr + r;
    ushort4 pk;
    pk.x = f2bf(o1[r][0] + er[r] * o2[r][0]);
    pk.y = f2bf(o1[r][1] + er[r] * o2[r][1]);
    pk.z = f2bf(o1[r][2] + er[r] * o2[r][2]);
    pk.w = f2bf(o1[r][3] + er[r] * o2[r][3]);
    *(ushort4*)&heb[((size_t)b * Nn_ + n) * 512 + h * 64 + tc] = pk;
  }
}

extern "C" void kernel_launch(void* const* d_in, const int* in_sizes, int n_in,
                              void* d_out, int out_size, void* d_ws, size_t ws_size,
                              hipStream_t stream) {
  const float* x     = (const float*)d_in[0];
  const float* ln1g  = (const float*)d_in[1];
  const float* ln1b  = (const float*)d_in[2];
  const float* ln2g  = (const float*)d_in[3];
  const float* ln2b  = (const float*)d_in[4];
  const float* ln3g  = (const float*)d_in[5];
  const float* ln3b  = (const float*)d_in[6];
  const float* w_pot = (const float*)d_in[7];
  const float* b_pot = (const float*)d_in[8];
  const float* w_bk  = (const float*)d_in[9];
  const float* b_bk  = (const float*)d_in[10];
  const float* w_qkv = (const float*)d_in[11];
  const float* b_qkv = (const float*)d_in[12];
  const float* w_out = (const float*)d_in[13];
  const float* b_out = (const float*)d_in[14];
  const float* w_ff1 = (const float*)d_in[15];
  const float* b_ff1 = (const float*)d_in[16];
  const float* w_ff2 = (const float*)d_in[17];
  const float* b_ff2 = (const float*)d_in[18];
  float* out = (float*)d_out;
  float* ws = (float*)d_ws;

  // ---- workspace layout (float units), total 32,571,392 floats = 130.3 MB ----
  float* V   = ws;
  float* gam = V + 8192;
  float* aRe = gam + 8192;
  float* aIm = aRe + 8192;
  float* bRe = aIm + 8192;
  float* bIm = bRe + 8192;
  float* Dc  = bIm + 8192;
  float* x1   = ws + 65536;            // 8.39M f32 (x1 residual)
  float* regB = x1 + 8388608;          // 8.39M f32: U+Win, later x2
  float* U    = regB;
  float* Win  = regB + 4194304;
  float* x2   = regB;
  float* regC = regB + 8388608;        // 6.29M f32: qkv bf16, later ff-hidden bf16
  unsigned short* qkvb = (unsigned short*)regC;
  unsigned short* hid  = (unsigned short*)regC;
  float* regD = regC + 6291456;        // 4.19M f32: xn bf16 / heb bf16 / xn3 bf16
  unsigned short* xnb = (unsigned short*)regD;
  unsigned short* heb = (unsigned short*)regD;
  unsigned short* wE  = (unsigned short*)(regD + 4194304);
  unsigned short* wqkvT = wE;                    // 1536x1024
  unsigned short* woutT = wqkvT + 1572864;       // 1024x512
  unsigned short* wff1T = woutT + 524288;        // 4096x1024
  unsigned short* wff2T = wff1T + 4194304;       // 1024x4096

  // weight transposes (fp32 KxN -> bf16 NxK)
  k_wt<<<dim3(1536 / 32, 1024 / 32), 256, 0, stream>>>(w_qkv, wqkvT, 1024, 1536);
  k_wt<<<dim3(1024 / 32, 512 / 32), 256, 0, stream>>>(w_out, woutT, 512, 1024);
  k_wt<<<dim3(4096 / 32, 1024 / 32), 256, 0, stream>>>(w_ff1, wff1T, 1024, 4096);
  k_wt<<<dim3(1024 / 32, 4096 / 32), 256, 0, stream>>>(w_ff2, wff2T, 4096, 1024);

  k_ln_pot<<<Tt, 256, 0, stream>>>(x, ln1g, ln1b, w_pot, b_pot, V, gam);
  k_cf<<<8, 64, 0, stream>>>(V, gam, aRe, aIm, bRe, bIm);
  k_bk_add<<<Tt, 256, 0, stream>>>(x, aRe, aIm, bRe, bIm, V, gam, w_bk, b_bk, x1);
  k_ln_bf<<<Tt, 256, 0, stream>>>(x1, ln2g, ln2b, xnb);
  // qkv: (8192x1024)@(1024x1536) -> bf16
  k_gemm_bf<<<dim3(1536 / 128, 8192 / 128), 256, 0, stream>>>(
      xnb, wqkvT, b_qkv, nullptr, qkvb, 8192, 1024, 1536, 4);
  k_heb_chunk<<<1024, 256, 0, stream>>>(qkvb, gam, U, Dc);
  k_heb_scan<<<32, 256, 0, stream>>>(U, Dc, Win);
  k_heb_out<<<1024, 256, 0, stream>>>(qkvb, gam, Win, heb);
  // out-proj: (8192x512)@(512x1024) + x1 -> f32 x2
  k_gemm_bf<<<dim3(1024 / 128, 8192 / 128), 256, 0, stream>>>(
      heb, woutT, b_out, x1, x2, 8192, 512, 1024, 2);
  k_ln_bf<<<Tt, 256, 0, stream>>>(x2, ln3g, ln3b, xnb);
  for (int sl = 0; sl < 4; sl++) {
    const size_t off = (size_t)sl * 2048 * 1024;
    // ff1: (2048x1024)@(1024x4096) gelu -> bf16
    k_gemm_bf<<<dim3(4096 / 128, 2048 / 128), 256, 0, stream>>>(
        xnb + off, wff1T, b_ff1, nullptr, hid, 2048, 1024, 4096, 1 | 4);
    // ff2: (2048x4096)@(4096x1024) + x2 -> f32 out
    k_gemm_bf<<<dim3(1024 / 128, 2048 / 128), 256, 0, stream>>>(
        hid, wff2T, b_ff2, x2 + off, out + off, 2048, 4096, 1024, 2);
  }
}

// Round 3
// 672.029 us; speedup vs baseline: 5.1948x; 1.5830x over previous
//
#include <hip/hip_runtime.h>

#define Bn 4
#define Nn_ 2048
#define Dd 1024
#define Hh 8
#define HDd 64
#define Tt 8192   // Bn*Nn_

typedef short s16x8 __attribute__((ext_vector_type(8)));
typedef float f32x4 __attribute__((ext_vector_type(4)));

__device__ __forceinline__ unsigned short f2bf(float f) {
  unsigned u = __float_as_uint(f);
  return (unsigned short)((u + 0x7fffu + ((u >> 16) & 1u)) >> 16);
}

__device__ __forceinline__ void bf8_to_f(const unsigned short* p, float* o) {
  const uint4 u = *(const uint4*)p;
  o[0] = __uint_as_float(u.x << 16);
  o[1] = __uint_as_float(u.x & 0xffff0000u);
  o[2] = __uint_as_float(u.y << 16);
  o[3] = __uint_as_float(u.y & 0xffff0000u);
  o[4] = __uint_as_float(u.z << 16);
  o[5] = __uint_as_float(u.z & 0xffff0000u);
  o[6] = __uint_as_float(u.w << 16);
  o[7] = __uint_as_float(u.w & 0xffff0000u);
}

__device__ __forceinline__ void gld16(const void* g, void* l) {
  __builtin_amdgcn_global_load_lds(
      (const __attribute__((address_space(1))) unsigned int*)(uintptr_t)g,
      (__attribute__((address_space(3))) unsigned int*)(uintptr_t)l, 16, 0, 0);
}

__device__ __forceinline__ void block_reduce2(float& a, float& b, float* sc) {
#pragma unroll
  for (int off = 32; off > 0; off >>= 1) {
    a += __shfl_down(a, off, 64);
    b += __shfl_down(b, off, 64);
  }
  __syncthreads();
  if ((threadIdx.x & 63) == 0) { int wid = threadIdx.x >> 6; sc[wid] = a; sc[4 + wid] = b; }
  __syncthreads();
  a = sc[0] + sc[1] + sc[2] + sc[3];
  b = sc[4] + sc[5] + sc[6] + sc[7];
}

__device__ __forceinline__ float gelu_f(float u) {
  const float c = 0.7978845608028654f * (u + 0.044715f * u * u * u);
  const float e = __expf(2.0f * c);
  const float th = 1.0f - 2.0f / (1.0f + e);
  return 0.5f * u * (1.0f + th);
}

// ---------- weight convert+transpose: W (KxN f32) -> WT (NxK bf16) ----------
__global__ __launch_bounds__(256) void k_wt(const float* __restrict__ W,
                                            unsigned short* __restrict__ WT, int K, int N) {
  __shared__ float tile[32][33];
  const int n0 = blockIdx.x * 32, k0 = blockIdx.y * 32;
  const int tx = threadIdx.x & 31, ty = threadIdx.x >> 5;  // ty 0..7
#pragma unroll
  for (int i = 0; i < 4; i++) {
    const int kk = ty + i * 8;
    tile[kk][tx] = W[(size_t)(k0 + kk) * N + n0 + tx];
  }
  __syncthreads();
#pragma unroll
  for (int i = 0; i < 4; i++) {
    const int nn = ty + i * 8;
    WT[(size_t)(n0 + nn) * K + k0 + tx] = f2bf(tile[tx][nn]);
  }
}

// ---------- LN1 + potential projection (V, gamma) ----------
__global__ __launch_bounds__(256) void k_ln_pot(
    const float* __restrict__ x, const float* __restrict__ g, const float* __restrict__ bt,
    const float* __restrict__ w_pot, const float* __restrict__ b_pot,
    float* __restrict__ V, float* __restrict__ gam) {
  __shared__ float sc[8];
  const int m = blockIdx.x, t = threadIdx.x;
  const float4 xv = ((const float4*)(x + (size_t)m * Dd))[t];
  float s = xv.x + xv.y + xv.z + xv.w;
  float ss = fmaf(xv.x, xv.x, fmaf(xv.y, xv.y, fmaf(xv.z, xv.z, xv.w * xv.w)));
  block_reduce2(s, ss, sc);
  const float mean = s * (1.0f / Dd);
  const float var = ss * (1.0f / Dd) - mean * mean;
  const float rs = rsqrtf(var + 1e-5f);
  const float4 gv = ((const float4*)g)[t];
  const float4 bv = ((const float4*)bt)[t];
  const float xn0 = (xv.x - mean) * rs * gv.x + bv.x;
  const float xn1 = (xv.y - mean) * rs * gv.y + bv.y;
  const float xn2 = (xv.z - mean) * rs * gv.z + bv.z;
  const float xn3 = (xv.w - mean) * rs * gv.w + bv.w;
  const float4 wp0 = ((const float4*)w_pot)[t * 2];
  const float4 wp1 = ((const float4*)w_pot)[t * 2 + 1];
  float s0 = xn0 * wp0.x + xn1 * wp0.z + xn2 * wp1.x + xn3 * wp1.z;
  float s1 = xn0 * wp0.y + xn1 * wp0.w + xn2 * wp1.y + xn3 * wp1.w;
  block_reduce2(s0, s1, sc);
  if (t == 0) {
    V[m] = s0 + b_pot[0];
    const float p1 = s1 + b_pot[1];
    const float sp = fmaxf(p1, 0.0f) + log1pf(expf(-fabsf(p1)));
    gam[m] = sp + 0.1f;
  }
}

// ---------- parallel continued fraction scan (Mobius matrix scan + replay) ----------
// chain = product of M_i = [[d_i,-1],[1,0]]; 64 lanes x 32-elem segments.
__global__ void k_cf_par(const float* __restrict__ V, const float* __restrict__ gam,
                         float* __restrict__ aRe, float* __restrict__ aIm,
                         float* __restrict__ bRe, float* __restrict__ bIm) {
  const int b = blockIdx.x >> 1, dir = blockIdx.x & 1;
  const int l = threadIdx.x;  // 0..63
  const float* Vb = V + b * Nn_;
  const float* gb = gam + b * Nn_;
  // m: [m00r,m00i,m01r,m01i,m10r,m10i,m11r,m11i], start = identity
  float m[8] = {1.f, 0.f, 0.f, 0.f, 0.f, 0.f, 1.f, 0.f};
#pragma unroll 4
  for (int s = 0; s < 32; s++) {
    const int j = l * 32 + s;
    const int i = dir ? (Nn_ - 1 - j) : j;
    const float dre = Vb[i] + 2.0f, dim = -gb[i];
    // new row0 = d*row0 - row1 ; new row1 = row0
    const float n00r = dre * m[0] - dim * m[1] - m[4];
    const float n00i = dre * m[1] + dim * m[0] - m[5];
    const float n01r = dre * m[2] - dim * m[3] - m[6];
    const float n01i = dre * m[3] + dim * m[2] - m[7];
    m[4] = m[0]; m[5] = m[1]; m[6] = m[2]; m[7] = m[3];
    m[0] = n00r; m[1] = n00i; m[2] = n01r; m[3] = n01i;
    const float rr = 1.0f / (fabsf(m[0]) + fabsf(m[1]) + fabsf(m[4]) + fabsf(m[5]));
#pragma unroll
    for (int q = 0; q < 8; q++) m[q] *= rr;
  }
  // inclusive Hillis-Steele scan: S_l = M_l * S_{l-1}  (own on LEFT)
#pragma unroll
  for (int off = 1; off < 64; off <<= 1) {
    float p[8];
#pragma unroll
    for (int q = 0; q < 8; q++) p[q] = __shfl_up(m[q], off, 64);
    if (l < off) { p[0] = 1.f; p[1] = 0.f; p[2] = 0.f; p[3] = 0.f;
                   p[4] = 0.f; p[5] = 0.f; p[6] = 1.f; p[7] = 0.f; }
    float c[8];
    c[0] = m[0] * p[0] - m[1] * p[1] + m[2] * p[4] - m[3] * p[5];
    c[1] = m[0] * p[1] + m[1] * p[0] + m[2] * p[5] + m[3] * p[4];
    c[2] = m[0] * p[2] - m[1] * p[3] + m[2] * p[6] - m[3] * p[7];
    c[3] = m[0] * p[3] + m[1] * p[2] + m[2] * p[7] + m[3] * p[6];
    c[4] = m[4] * p[0] - m[5] * p[1] + m[6] * p[4] - m[7] * p[5];
    c[5] = m[4] * p[1] + m[5] * p[0] + m[6] * p[5] + m[7] * p[4];
    c[6] = m[4] * p[2] - m[5] * p[3] + m[6] * p[6] - m[7] * p[7];
    c[7] = m[4] * p[3] + m[5] * p[2] + m[6] * p[7] + m[7] * p[6];
    const float rr = 1.0f / (fabsf(c[0]) + fabsf(c[1]) + fabsf(c[4]) + fabsf(c[5]));
#pragma unroll
    for (int q = 0; q < 8; q++) m[q] = c[q] * rr;
  }
  // exclusive prefix
  float e[8];
#pragma unroll
  for (int q = 0; q < 8; q++) e[q] = __shfl_up(m[q], 1, 64);
  if (l == 0) { e[0] = 1.f; e[1] = 0.f; e[4] = 0.f; e[5] = 0.f; }
  // seed: (nu,de) = E*(1,0) = (e00, e10); 1/a_prev = de/nu = de*conj(nu)/|nu|^2
  const float inr = 1.0f / (e[0] * e[0] + e[1] * e[1]);
  float pr = (e[4] * e[0] + e[5] * e[1]) * inr;
  float pi = (e[5] * e[0] - e[4] * e[1]) * inr;
  // replay original recurrence over segment
  float* oR = dir ? bRe : aRe;
  float* oI = dir ? bIm : aIm;
#pragma unroll 4
  for (int s = 0; s < 32; s++) {
    const int j = l * 32 + s;
    const int i = dir ? (Nn_ - 1 - j) : j;
    const float dre = Vb[i] + 2.0f, dim = -gb[i];
    const float ar = dre - pr, ai = dim - pi;
    oR[b * Nn_ + i] = ar; oI[b * Nn_ + i] = ai;
    const float r = 1.0f / (ar * ar + ai * ai);
    pr = ar * r; pi = -ai * r;
  }
}

// ---------- x1 = x + [G.re,G.im] @ w_bk + b_bk ----------
__global__ __launch_bounds__(256) void k_bk_add(
    const float* __restrict__ x, const float* __restrict__ aRe, const float* __restrict__ aIm,
    const float* __restrict__ bRe, const float* __restrict__ bIm,
    const float* __restrict__ V, const float* __restrict__ gam,
    const float* __restrict__ w_bk, const float* __restrict__ b_bk, float* __restrict__ x1) {
  const int m = blockIdx.x, t = threadIdx.x;
  const float dre = V[m] + 2.0f, dim = -gam[m];
  const float nr = aRe[m] + bRe[m] - dre;
  const float ni = aIm[m] + bIm[m] - dim;
  const float r = 1.0f / (nr * nr + ni * ni);
  const float Gre = nr * r, Gim = -ni * r;
  const float4 xv = ((const float4*)(x + (size_t)m * Dd))[t];
  const float4 w0 = ((const float4*)w_bk)[t];
  const float4 w1 = ((const float4*)(w_bk + Dd))[t];
  const float4 bb = ((const float4*)b_bk)[t];
  float4 o;
  o.x = xv.x + Gre * w0.x + Gim * w1.x + bb.x;
  o.y = xv.y + Gre * w0.y + Gim * w1.y + bb.y;
  o.z = xv.z + Gre * w0.z + Gim * w1.z + bb.z;
  o.w = xv.w + Gre * w0.w + Gim * w1.w + bb.w;
  ((float4*)(x1 + (size_t)m * Dd))[t] = o;
}

// ---------- layernorm -> bf16 output ----------
__global__ __launch_bounds__(256) void k_ln_bf(
    const float* __restrict__ x, const float* __restrict__ g, const float* __restrict__ bt,
    unsigned short* __restrict__ y) {
  __shared__ float sc[8];
  const int m = blockIdx.x, t = threadIdx.x;
  const float4 xv = ((const float4*)(x + (size_t)m * Dd))[t];
  float s = xv.x + xv.y + xv.z + xv.w;
  float ss = fmaf(xv.x, xv.x, fmaf(xv.y, xv.y, fmaf(xv.z, xv.z, xv.w * xv.w)));
  block_reduce2(s, ss, sc);
  const float mean = s * (1.0f / Dd);
  const float var = ss * (1.0f / Dd) - mean * mean;
  const float rs = rsqrtf(var + 1e-5f);
  const float4 gv = ((const float4*)g)[t];
  const float4 bv = ((const float4*)bt)[t];
  ushort4 pk;
  pk.x = f2bf((xv.x - mean) * rs * gv.x + bv.x);
  pk.y = f2bf((xv.y - mean) * rs * gv.y + bv.y);
  pk.z = f2bf((xv.z - mean) * rs * gv.z + bv.z);
  pk.w = f2bf((xv.w - mean) * rs * gv.w + bv.w);
  ((ushort4*)(y + (size_t)m * Dd))[t] = pk;
}

// ---------- bf16 MFMA GEMM: C = A(MxK) @ BT(NxK)^T + bias; epilogue flags ----------
// flags: 1=gelu, 2=add fp32 res, 4=store bf16 (else fp32)
__global__ __launch_bounds__(256) void k_gemm_bf(
    const unsigned short* __restrict__ A, const unsigned short* __restrict__ BT,
    const float* __restrict__ bias, const float* __restrict__ res,
    void* __restrict__ C, int M, int K, int N, int flags) {
  __shared__ unsigned short As[128 * 32];
  __shared__ unsigned short Bs[128 * 32];
  const int t = threadIdx.x;
  const int n0 = blockIdx.x * 128;
  const int m0 = blockIdx.y * 128;
  const int lane = t & 63;
  const int w = t >> 6;
  const int wr = (w >> 1) * 64, wc = (w & 1) * 64;
  const int mrow = lane & 15;
  const int kq = (lane >> 4) * 8;

  f32x4 acc[4][4];
#pragma unroll
  for (int i = 0; i < 4; i++)
#pragma unroll
    for (int j = 0; j < 4; j++) acc[i][j] = (f32x4){0.f, 0.f, 0.f, 0.f};

  for (int kt = 0; kt < K; kt += 32) {
#pragma unroll
    for (int l = 0; l < 2; l++) {
      const int idx = t + 256 * l;       // 0..511, 8 bf16 each
      const int row = idx >> 2;
      const int col = (idx & 3) * 8;
      gld16(A + (size_t)(m0 + row) * K + kt + col, As + idx * 8);
      gld16(BT + (size_t)(n0 + row) * K + kt + col, Bs + idx * 8);
    }
    __syncthreads();
    s16x8 aF[4], bF[4];
#pragma unroll
    for (int i = 0; i < 4; i++) {
      aF[i] = *(const s16x8*)(As + (wr + i * 16 + mrow) * 32 + kq);
      bF[i] = *(const s16x8*)(Bs + (wc + i * 16 + mrow) * 32 + kq);
    }
#pragma unroll
    for (int i = 0; i < 4; i++)
#pragma unroll
      for (int j = 0; j < 4; j++)
        acc[i][j] = __builtin_amdgcn_mfma_f32_16x16x32_bf16(aF[i], bF[j], acc[i][j], 0, 0, 0);
    __syncthreads();
  }

  float bsv[4];
#pragma unroll
  for (int j = 0; j < 4; j++) bsv[j] = bias[n0 + wc + j * 16 + (lane & 15)];
  const int r0 = m0 + wr + (lane >> 4) * 4;
#pragma unroll
  for (int i = 0; i < 4; i++) {
#pragma unroll
    for (int rg = 0; rg < 4; rg++) {
      const size_t row = (size_t)(r0 + i * 16 + rg);
#pragma unroll
      for (int j = 0; j < 4; j++) {
        const int col = n0 + wc + j * 16 + (lane & 15);
        float v = acc[i][j][rg] + bsv[j];
        if (flags & 1) v = gelu_f(v);
        if (flags & 2) v += res[row * N + col];
        if (flags & 4) ((unsigned short*)C)[row * N + col] = f2bf(v);
        else ((float*)C)[row * N + col] = v;
      }
    }
  }
}

// ---------- Hebbian phase A: per-chunk decayed outer-product sums ----------
__global__ __launch_bounds__(256) void k_heb_chunk(
    const unsigned short* __restrict__ qkv, const float* __restrict__ gam,
    float* __restrict__ U, float* __restrict__ Dc) {
  __shared__ float kw[4096];
  __shared__ float vS[4096];
  __shared__ float cum[64];
  const int bx = blockIdx.x;
  const int c = bx & 31, bh = bx >> 5, b = bh >> 3, h = bh & 7;
  const int t = threadIdx.x;
  const int n0 = c * 64;
  const size_t base = ((size_t)(b * Nn_ + n0)) * 1536 + h * 64;
#pragma unroll
  for (int l = 0; l < 2; l++) {
    const int idx8 = t + 256 * l;       // 0..511
    const int s = idx8 >> 3;
    const int d0 = (idx8 & 7) << 3;
    const size_t gi = base + (size_t)s * 1536 + d0;
    bf8_to_f(qkv + gi + 512, &kw[s * 64 + d0]);
    bf8_to_f(qkv + gi + 1024, &vS[s * 64 + d0]);
  }
  if (t < 64) {
    float val = 0.01f * gam[b * Nn_ + n0 + t];
#pragma unroll
    for (int off = 1; off < 64; off <<= 1) {
      const float o = __shfl_up(val, off, 64);
      if (t >= off) val += o;
    }
    cum[t] = val;
  }
  __syncthreads();
  const float total = cum[63];
#pragma unroll
  for (int l = 0; l < 16; l++) {
    const int idx = t + 256 * l;
    const int s = idx >> 6;
    kw[idx] *= 0.1f * __expf(cum[s] - total);
  }
  __syncthreads();
  const int td = (t & 15) << 2, te = (t >> 4) << 2;
  float acc[4][4];
#pragma unroll
  for (int i = 0; i < 4; i++)
#pragma unroll
    for (int j = 0; j < 4; j++) acc[i][j] = 0.0f;
  for (int s = 0; s < 64; s++) {
    const float4 kk = *(const float4*)&kw[s * 64 + td];
    const float4 vv = *(const float4*)&vS[s * 64 + te];
    const float ka[4] = {kk.x, kk.y, kk.z, kk.w};
    const float va[4] = {vv.x, vv.y, vv.z, vv.w};
#pragma unroll
    for (int i = 0; i < 4; i++)
#pragma unroll
      for (int j = 0; j < 4; j++) acc[i][j] = fmaf(ka[i], va[j], acc[i][j]);
  }
  float* Up = U + (size_t)bx * 4096;
#pragma unroll
  for (int i = 0; i < 4; i++)
#pragma unroll
    for (int j = 0; j < 4; j++) Up[(td + i) * 64 + te + j] = acc[i][j];
  if (t == 0) Dc[bx] = __expf(-total);
}

// ---------- Hebbian phase B: carry W across chunks (one thread per element) ----------
__global__ __launch_bounds__(256) void k_heb_scan(
    const float* __restrict__ U, const float* __restrict__ Dc, float* __restrict__ Win) {
  const int gid = blockIdx.x * 256 + threadIdx.x;   // 0..131071
  const int bh = gid >> 12, el = gid & 4095;
  float w = 0.0f;
#pragma unroll 4
  for (int c = 0; c < 32; c++) {
    const size_t idx = (((size_t)(bh * 32 + c)) << 12) + el;
    Win[idx] = w;
    w = Dc[bh * 32 + c] * w + U[idx];
  }
}

// ---------- Hebbian phase C: intra-chunk causal + inter-chunk q@W_in ----------
__global__ __launch_bounds__(256) void k_heb_out(
    const unsigned short* __restrict__ qkv, const float* __restrict__ gam,
    const float* __restrict__ Win, unsigned short* __restrict__ heb) {
  __shared__ float qS[4096];
  __shared__ float kT[4096];
  __shared__ float vS[4096];
  __shared__ float P[4096];
  const int bx = blockIdx.x;
  const int c = bx & 31, bh = bx >> 5, b = bh >> 3, h = bh & 7;
  const int t = threadIdx.x;
  const int n0 = c * 64;
  const size_t base = ((size_t)(b * Nn_ + n0)) * 1536 + h * 64;
#pragma unroll
  for (int l = 0; l < 2; l++) {
    const int idx8 = t + 256 * l;
    const int s = idx8 >> 3;
    const int d0 = (idx8 & 7) << 3;
    const size_t gi = base + (size_t)s * 1536 + d0;
    bf8_to_f(qkv + gi, &qS[s * 64 + d0]);
    bf8_to_f(qkv + gi + 1024, &vS[s * 64 + d0]);
    float tmp[8];
    bf8_to_f(qkv + gi + 512, tmp);
#pragma unroll
    for (int j = 0; j < 8; j++) kT[(d0 + j) * 64 + s] = tmp[j];
  }
  if (t < 64) {
    float val = 0.01f * gam[b * Nn_ + n0 + t];
#pragma unroll
    for (int off = 1; off < 64; off <<= 1) {
      const float o = __shfl_up(val, off, 64);
      if (t >= off) val += o;
    }
    P[t] = val;
  }
  __syncthreads();
  const int tr = (t >> 4) << 2;
  const int tc = (t & 15) << 2;
  float er[4], es[4];
#pragma unroll
  for (int r = 0; r < 4; r++) er[r] = __expf(-P[tr + r]);
#pragma unroll
  for (int j = 0; j < 4; j++) es[j] = 0.1f * __expf(P[tc + j]);
  __syncthreads();
  float acc[4][4];
#pragma unroll
  for (int i = 0; i < 4; i++)
#pragma unroll
    for (int j = 0; j < 4; j++) acc[i][j] = 0.0f;
  for (int d = 0; d < 64; d++) {
    const float4 kk = *(const float4*)&kT[d * 64 + tc];
    const float ka[4] = {kk.x, kk.y, kk.z, kk.w};
#pragma unroll
    for (int r = 0; r < 4; r++) {
      const float qv = qS[(tr + r) * 64 + d];
#pragma unroll
      for (int j = 0; j < 4; j++) acc[r][j] = fmaf(qv, ka[j], acc[r][j]);
    }
  }
#pragma unroll
  for (int r = 0; r < 4; r++)
#pragma unroll
    for (int j = 0; j < 4; j++) {
      const int tt = tr + r, ssi = tc + j;
      const float wgt = (ssi <= tt) ? er[r] * es[j] : 0.0f;
      P[tt * 64 + ssi] = acc[r][j] * wgt;
    }
  __syncthreads();
  const size_t wb = (size_t)bx * 4096;
#pragma unroll
  for (int l = 0; l < 16; l++) {
    const int idx = t + 256 * l;
    kT[idx] = Win[wb + idx];
  }
  __syncthreads();
  float o1[4][4], o2[4][4];
#pragma unroll
  for (int i = 0; i < 4; i++)
#pragma unroll
    for (int j = 0; j < 4; j++) { o1[i][j] = 0.0f; o2[i][j] = 0.0f; }
  for (int s = 0; s < 64; s++) {
    const float4 vv = *(const float4*)&vS[s * 64 + tc];
    const float4 ww = *(const float4*)&kT[s * 64 + tc];
    const float va[4] = {vv.x, vv.y, vv.z, vv.w};
    const float wa[4] = {ww.x, ww.y, ww.z, ww.w};
#pragma unroll
    for (int r = 0; r < 4; r++) {
      const float pv = P[(tr + r) * 64 + s];
      const float qv = qS[(tr + r) * 64 + s];
#pragma unroll
      for (int j = 0; j < 4; j++) {
        o1[r][j] = fmaf(pv, va[j], o1[r][j]);
        o2[r][j] = fmaf(qv, wa[j], o2[r][j]);
      }
    }
  }
#pragma unroll
  for (int r = 0; r < 4; r++) {
    const int n = n0 + tr + r;
    ushort4 pk;
    pk.x = f2bf(o1[r][0] + er[r] * o2[r][0]);
    pk.y = f2bf(o1[r][1] + er[r] * o2[r][1]);
    pk.z = f2bf(o1[r][2] + er[r] * o2[r][2]);
    pk.w = f2bf(o1[r][3] + er[r] * o2[r][3]);
    *(ushort4*)&heb[((size_t)b * Nn_ + n) * 512 + h * 64 + tc] = pk;
  }
}

extern "C" void kernel_launch(void* const* d_in, const int* in_sizes, int n_in,
                              void* d_out, int out_size, void* d_ws, size_t ws_size,
                              hipStream_t stream) {
  const float* x     = (const float*)d_in[0];
  const float* ln1g  = (const float*)d_in[1];
  const float* ln1b  = (const float*)d_in[2];
  const float* ln2g  = (const float*)d_in[3];
  const float* ln2b  = (const float*)d_in[4];
  const float* ln3g  = (const float*)d_in[5];
  const float* ln3b  = (const float*)d_in[6];
  const float* w_pot = (const float*)d_in[7];
  const float* b_pot = (const float*)d_in[8];
  const float* w_bk  = (const float*)d_in[9];
  const float* b_bk  = (const float*)d_in[10];
  const float* w_qkv = (const float*)d_in[11];
  const float* b_qkv = (const float*)d_in[12];
  const float* w_out = (const float*)d_in[13];
  const float* b_out = (const float*)d_in[14];
  const float* w_ff1 = (const float*)d_in[15];
  const float* b_ff1 = (const float*)d_in[16];
  const float* w_ff2 = (const float*)d_in[17];
  const float* b_ff2 = (const float*)d_in[18];
  float* out = (float*)d_out;
  float* ws = (float*)d_ws;

  // ---- workspace layout (float units) ----
  float* V   = ws;
  float* gam = V + 8192;
  float* aRe = gam + 8192;
  float* aIm = aRe + 8192;
  float* bRe = aIm + 8192;
  float* bIm = bRe + 8192;
  float* Dc  = bIm + 8192;
  float* x1   = ws + 65536;            // 8.39M f32: x1 residual, later ff hidden (bf16)
  float* regB = x1 + 8388608;          // 8.39M f32: U+Win, later x2
  float* U    = regB;
  float* Win  = regB + 4194304;
  float* x2   = regB;
  float* regC = regB + 8388608;        // 6.29M f32: qkv bf16
  unsigned short* qkvb = (unsigned short*)regC;
  float* regD = regC + 6291456;        // 4.19M f32: xn bf16 / heb bf16 / xn3 bf16
  unsigned short* xnb = (unsigned short*)regD;
  unsigned short* heb = (unsigned short*)regD;
  unsigned short* wE  = (unsigned short*)(regD + 4194304);
  unsigned short* wqkvT = wE;                    // 1536x1024
  unsigned short* woutT = wqkvT + 1572864;       // 1024x512
  unsigned short* wff1T = woutT + 524288;        // 4096x1024
  unsigned short* wff2T = wff1T + 4194304;       // 1024x4096
  unsigned short* hid = (unsigned short*)x1;     // ff hidden slab (4096x4096 bf16)

  // weight transposes (fp32 KxN -> bf16 NxK)
  k_wt<<<dim3(1536 / 32, 1024 / 32), 256, 0, stream>>>(w_qkv, wqkvT, 1024, 1536);
  k_wt<<<dim3(1024 / 32, 512 / 32), 256, 0, stream>>>(w_out, woutT, 512, 1024);
  k_wt<<<dim3(4096 / 32, 1024 / 32), 256, 0, stream>>>(w_ff1, wff1T, 1024, 4096);
  k_wt<<<dim3(1024 / 32, 4096 / 32), 256, 0, stream>>>(w_ff2, wff2T, 4096, 1024);

  k_ln_pot<<<Tt, 256, 0, stream>>>(x, ln1g, ln1b, w_pot, b_pot, V, gam);
  k_cf_par<<<8, 64, 0, stream>>>(V, gam, aRe, aIm, bRe, bIm);
  k_bk_add<<<Tt, 256, 0, stream>>>(x, aRe, aIm, bRe, bIm, V, gam, w_bk, b_bk, x1);
  k_ln_bf<<<Tt, 256, 0, stream>>>(x1, ln2g, ln2b, xnb);
  // qkv: (8192x1024)@(1024x1536) -> bf16
  k_gemm_bf<<<dim3(1536 / 128, 8192 / 128), 256, 0, stream>>>(
      xnb, wqkvT, b_qkv, nullptr, qkvb, 8192, 1024, 1536, 4);
  k_heb_chunk<<<1024, 256, 0, stream>>>(qkvb, gam, U, Dc);
  k_heb_scan<<<512, 256, 0, stream>>>(U, Dc, Win);
  k_heb_out<<<1024, 256, 0, stream>>>(qkvb, gam, Win, heb);
  // out-proj: (8192x512)@(512x1024) + x1 -> f32 x2
  k_gemm_bf<<<dim3(1024 / 128, 8192 / 128), 256, 0, stream>>>(
      heb, woutT, b_out, x1, x2, 8192, 512, 1024, 2);
  k_ln_bf<<<Tt, 256, 0, stream>>>(x2, ln3g, ln3b, xnb);
  for (int sl = 0; sl < 2; sl++) {
    const size_t off = (size_t)sl * 4096 * 1024;
    // ff1: (4096x1024)@(1024x4096) gelu -> bf16  (hid reuses dead x1 region)
    k_gemm_bf<<<dim3(4096 / 128, 4096 / 128), 256, 0, stream>>>(
        xnb + off, wff1T, b_ff1, nullptr, hid, 4096, 1024, 4096, 1 | 4);
    // ff2: (4096x4096)@(4096x1024) + x2 -> f32 out
    k_gemm_bf<<<dim3(1024 / 128, 4096 / 128), 256, 0, stream>>>(
        hid, wff2T, b_ff2, x2 + off, out + off, 4096, 4096, 1024, 2);
  }
}

// Round 4
// 559.620 us; speedup vs baseline: 6.2382x; 1.2009x over previous
//
#include <hip/hip_runtime.h>

#define Bn 4
#define Nn_ 2048
#define Dd 1024
#define Hh 8
#define HDd 64
#define Tt 8192   // Bn*Nn_

typedef short s16x8 __attribute__((ext_vector_type(8)));
typedef float f32x4 __attribute__((ext_vector_type(4)));
typedef float f32x16 __attribute__((ext_vector_type(16)));

__device__ __forceinline__ unsigned short f2bf(float f) {
  unsigned u = __float_as_uint(f);
  return (unsigned short)((u + 0x7fffu + ((u >> 16) & 1u)) >> 16);
}

__device__ __forceinline__ void bf8_to_f(const unsigned short* p, float* o) {
  const uint4 u = *(const uint4*)p;
  o[0] = __uint_as_float(u.x << 16);
  o[1] = __uint_as_float(u.x & 0xffff0000u);
  o[2] = __uint_as_float(u.y << 16);
  o[3] = __uint_as_float(u.y & 0xffff0000u);
  o[4] = __uint_as_float(u.z << 16);
  o[5] = __uint_as_float(u.z & 0xffff0000u);
  o[6] = __uint_as_float(u.w << 16);
  o[7] = __uint_as_float(u.w & 0xffff0000u);
}

__device__ __forceinline__ void gld16(const void* g, void* l) {
  __builtin_amdgcn_global_load_lds(
      (const __attribute__((address_space(1))) unsigned int*)(uintptr_t)g,
      (__attribute__((address_space(3))) unsigned int*)(uintptr_t)l, 16, 0, 0);
}

__device__ __forceinline__ void block_reduce2(float& a, float& b, float* sc) {
#pragma unroll
  for (int off = 32; off > 0; off >>= 1) {
    a += __shfl_down(a, off, 64);
    b += __shfl_down(b, off, 64);
  }
  __syncthreads();
  if ((threadIdx.x & 63) == 0) { int wid = threadIdx.x >> 6; sc[wid] = a; sc[4 + wid] = b; }
  __syncthreads();
  a = sc[0] + sc[1] + sc[2] + sc[3];
  b = sc[4] + sc[5] + sc[6] + sc[7];
}

__device__ __forceinline__ float gelu_f(float u) {
  const float c = 0.7978845608028654f * (u + 0.044715f * u * u * u);
  const float e = __expf(2.0f * c);
  const float th = 1.0f - 2.0f / (1.0f + e);
  return 0.5f * u * (1.0f + th);
}

// ---------- weight convert+transpose: W (KxN f32) -> WT (NxK bf16) ----------
__global__ __launch_bounds__(256) void k_wt(const float* __restrict__ W,
                                            unsigned short* __restrict__ WT, int K, int N) {
  __shared__ float tile[32][33];
  const int n0 = blockIdx.x * 32, k0 = blockIdx.y * 32;
  const int tx = threadIdx.x & 31, ty = threadIdx.x >> 5;  // ty 0..7
#pragma unroll
  for (int i = 0; i < 4; i++) {
    const int kk = ty + i * 8;
    tile[kk][tx] = W[(size_t)(k0 + kk) * N + n0 + tx];
  }
  __syncthreads();
#pragma unroll
  for (int i = 0; i < 4; i++) {
    const int nn = ty + i * 8;
    WT[(size_t)(n0 + nn) * K + k0 + tx] = f2bf(tile[tx][nn]);
  }
}

// ---------- LN1 + potential projection (V, gamma) ----------
__global__ __launch_bounds__(256) void k_ln_pot(
    const float* __restrict__ x, const float* __restrict__ g, const float* __restrict__ bt,
    const float* __restrict__ w_pot, const float* __restrict__ b_pot,
    float* __restrict__ V, float* __restrict__ gam) {
  __shared__ float sc[8];
  const int m = blockIdx.x, t = threadIdx.x;
  const float4 xv = ((const float4*)(x + (size_t)m * Dd))[t];
  float s = xv.x + xv.y + xv.z + xv.w;
  float ss = fmaf(xv.x, xv.x, fmaf(xv.y, xv.y, fmaf(xv.z, xv.z, xv.w * xv.w)));
  block_reduce2(s, ss, sc);
  const float mean = s * (1.0f / Dd);
  const float var = ss * (1.0f / Dd) - mean * mean;
  const float rs = rsqrtf(var + 1e-5f);
  const float4 gv = ((const float4*)g)[t];
  const float4 bv = ((const float4*)bt)[t];
  const float xn0 = (xv.x - mean) * rs * gv.x + bv.x;
  const float xn1 = (xv.y - mean) * rs * gv.y + bv.y;
  const float xn2 = (xv.z - mean) * rs * gv.z + bv.z;
  const float xn3 = (xv.w - mean) * rs * gv.w + bv.w;
  const float4 wp0 = ((const float4*)w_pot)[t * 2];
  const float4 wp1 = ((const float4*)w_pot)[t * 2 + 1];
  float s0 = xn0 * wp0.x + xn1 * wp0.z + xn2 * wp1.x + xn3 * wp1.z;
  float s1 = xn0 * wp0.y + xn1 * wp0.w + xn2 * wp1.y + xn3 * wp1.w;
  block_reduce2(s0, s1, sc);
  if (t == 0) {
    V[m] = s0 + b_pot[0];
    const float p1 = s1 + b_pot[1];
    const float sp = fmaxf(p1, 0.0f) + log1pf(expf(-fabsf(p1)));
    gam[m] = sp + 0.1f;
  }
}

// ---------- parallel continued fraction scan (Mobius matrix scan + replay) ----------
__global__ void k_cf_par(const float* __restrict__ V, const float* __restrict__ gam,
                         float* __restrict__ aRe, float* __restrict__ aIm,
                         float* __restrict__ bRe, float* __restrict__ bIm) {
  const int b = blockIdx.x >> 1, dir = blockIdx.x & 1;
  const int l = threadIdx.x;  // 0..63
  const float* Vb = V + b * Nn_;
  const float* gb = gam + b * Nn_;
  float m[8] = {1.f, 0.f, 0.f, 0.f, 0.f, 0.f, 1.f, 0.f};
#pragma unroll 4
  for (int s = 0; s < 32; s++) {
    const int j = l * 32 + s;
    const int i = dir ? (Nn_ - 1 - j) : j;
    const float dre = Vb[i] + 2.0f, dim = -gb[i];
    const float n00r = dre * m[0] - dim * m[1] - m[4];
    const float n00i = dre * m[1] + dim * m[0] - m[5];
    const float n01r = dre * m[2] - dim * m[3] - m[6];
    const float n01i = dre * m[3] + dim * m[2] - m[7];
    m[4] = m[0]; m[5] = m[1]; m[6] = m[2]; m[7] = m[3];
    m[0] = n00r; m[1] = n00i; m[2] = n01r; m[3] = n01i;
    const float rr = 1.0f / (fabsf(m[0]) + fabsf(m[1]) + fabsf(m[4]) + fabsf(m[5]));
#pragma unroll
    for (int q = 0; q < 8; q++) m[q] *= rr;
  }
#pragma unroll
  for (int off = 1; off < 64; off <<= 1) {
    float p[8];
#pragma unroll
    for (int q = 0; q < 8; q++) p[q] = __shfl_up(m[q], off, 64);
    if (l < off) { p[0] = 1.f; p[1] = 0.f; p[2] = 0.f; p[3] = 0.f;
                   p[4] = 0.f; p[5] = 0.f; p[6] = 1.f; p[7] = 0.f; }
    float c[8];
    c[0] = m[0] * p[0] - m[1] * p[1] + m[2] * p[4] - m[3] * p[5];
    c[1] = m[0] * p[1] + m[1] * p[0] + m[2] * p[5] + m[3] * p[4];
    c[2] = m[0] * p[2] - m[1] * p[3] + m[2] * p[6] - m[3] * p[7];
    c[3] = m[0] * p[3] + m[1] * p[2] + m[2] * p[7] + m[3] * p[6];
    c[4] = m[4] * p[0] - m[5] * p[1] + m[6] * p[4] - m[7] * p[5];
    c[5] = m[4] * p[1] + m[5] * p[0] + m[6] * p[5] + m[7] * p[4];
    c[6] = m[4] * p[2] - m[5] * p[3] + m[6] * p[6] - m[7] * p[7];
    c[7] = m[4] * p[3] + m[5] * p[2] + m[6] * p[7] + m[7] * p[6];
    const float rr = 1.0f / (fabsf(c[0]) + fabsf(c[1]) + fabsf(c[4]) + fabsf(c[5]));
#pragma unroll
    for (int q = 0; q < 8; q++) m[q] = c[q] * rr;
  }
  float e[8];
#pragma unroll
  for (int q = 0; q < 8; q++) e[q] = __shfl_up(m[q], 1, 64);
  if (l == 0) { e[0] = 1.f; e[1] = 0.f; e[4] = 0.f; e[5] = 0.f; }
  const float inr = 1.0f / (e[0] * e[0] + e[1] * e[1]);
  float pr = (e[4] * e[0] + e[5] * e[1]) * inr;
  float pi = (e[5] * e[0] - e[4] * e[1]) * inr;
  float* oR = dir ? bRe : aRe;
  float* oI = dir ? bIm : aIm;
#pragma unroll 4
  for (int s = 0; s < 32; s++) {
    const int j = l * 32 + s;
    const int i = dir ? (Nn_ - 1 - j) : j;
    const float dre = Vb[i] + 2.0f, dim = -gb[i];
    const float ar = dre - pr, ai = dim - pi;
    oR[b * Nn_ + i] = ar; oI[b * Nn_ + i] = ai;
    const float r = 1.0f / (ar * ar + ai * ai);
    pr = ar * r; pi = -ai * r;
  }
}

// ---------- x1 = x + [G.re,G.im] @ w_bk + b_bk ----------
__global__ __launch_bounds__(256) void k_bk_add(
    const float* __restrict__ x, const float* __restrict__ aRe, const float* __restrict__ aIm,
    const float* __restrict__ bRe, const float* __restrict__ bIm,
    const float* __restrict__ V, const float* __restrict__ gam,
    const float* __restrict__ w_bk, const float* __restrict__ b_bk, float* __restrict__ x1) {
  const int m = blockIdx.x, t = threadIdx.x;
  const float dre = V[m] + 2.0f, dim = -gam[m];
  const float nr = aRe[m] + bRe[m] - dre;
  const float ni = aIm[m] + bIm[m] - dim;
  const float r = 1.0f / (nr * nr + ni * ni);
  const float Gre = nr * r, Gim = -ni * r;
  const float4 xv = ((const float4*)(x + (size_t)m * Dd))[t];
  const float4 w0 = ((const float4*)w_bk)[t];
  const float4 w1 = ((const float4*)(w_bk + Dd))[t];
  const float4 bb = ((const float4*)b_bk)[t];
  float4 o;
  o.x = xv.x + Gre * w0.x + Gim * w1.x + bb.x;
  o.y = xv.y + Gre * w0.y + Gim * w1.y + bb.y;
  o.z = xv.z + Gre * w0.z + Gim * w1.z + bb.z;
  o.w = xv.w + Gre * w0.w + Gim * w1.w + bb.w;
  ((float4*)(x1 + (size_t)m * Dd))[t] = o;
}

// ---------- layernorm -> bf16 output ----------
__global__ __launch_bounds__(256) void k_ln_bf(
    const float* __restrict__ x, const float* __restrict__ g, const float* __restrict__ bt,
    unsigned short* __restrict__ y) {
  __shared__ float sc[8];
  const int m = blockIdx.x, t = threadIdx.x;
  const float4 xv = ((const float4*)(x + (size_t)m * Dd))[t];
  float s = xv.x + xv.y + xv.z + xv.w;
  float ss = fmaf(xv.x, xv.x, fmaf(xv.y, xv.y, fmaf(xv.z, xv.z, xv.w * xv.w)));
  block_reduce2(s, ss, sc);
  const float mean = s * (1.0f / Dd);
  const float var = ss * (1.0f / Dd) - mean * mean;
  const float rs = rsqrtf(var + 1e-5f);
  const float4 gv = ((const float4*)g)[t];
  const float4 bv = ((const float4*)bt)[t];
  ushort4 pk;
  pk.x = f2bf((xv.x - mean) * rs * gv.x + bv.x);
  pk.y = f2bf((xv.y - mean) * rs * gv.y + bv.y);
  pk.z = f2bf((xv.z - mean) * rs * gv.z + bv.z);
  pk.w = f2bf((xv.w - mean) * rs * gv.w + bv.w);
  ((ushort4*)(y + (size_t)m * Dd))[t] = pk;
}

// ---------- bf16 MFMA GEMM (32x32x16): C = A(MxK) @ BT(NxK)^T + bias ----------
// flags: 1=gelu, 2=add fp32 res, 4=store bf16 (else fp32)
__global__ __launch_bounds__(256) void k_gemm_bf(
    const unsigned short* __restrict__ A, const unsigned short* __restrict__ BT,
    const float* __restrict__ bias, const float* __restrict__ res,
    void* __restrict__ C, int M, int K, int N, int flags) {
  __shared__ unsigned short As[128 * 32];
  __shared__ unsigned short Bs[128 * 32];
  const int t = threadIdx.x;
  const int n0 = blockIdx.x * 128;
  const int m0 = blockIdx.y * 128;
  const int lane = t & 63;
  const int w = t >> 6;
  const int wr = (w >> 1) * 64, wc = (w & 1) * 64;  // wave's 64x64 quadrant
  const int r32 = lane & 31;        // row/col within a 32-tile
  const int ks = (lane >> 5) * 8;   // k-half offset

  // staging pointers (hoisted; advance by 32 elems/iter)
  const int srow = t >> 2, scol = (t & 3) * 8;
  const unsigned short* gA0 = A + (size_t)(m0 + srow) * K + scol;
  const unsigned short* gA1 = A + (size_t)(m0 + srow + 64) * K + scol;
  const unsigned short* gB0 = BT + (size_t)(n0 + srow) * K + scol;
  const unsigned short* gB1 = BT + (size_t)(n0 + srow + 64) * K + scol;
  unsigned short* lA0 = As + t * 8;
  unsigned short* lA1 = As + (t + 256) * 8;
  unsigned short* lB0 = Bs + t * 8;
  unsigned short* lB1 = Bs + (t + 256) * 8;

  f32x16 acc[2][2];
#pragma unroll
  for (int i = 0; i < 2; i++)
#pragma unroll
    for (int j = 0; j < 2; j++)
#pragma unroll
      for (int q = 0; q < 16; q++) acc[i][j][q] = 0.0f;

  for (int kt = 0; kt < K; kt += 32) {
    gld16(gA0 + kt, lA0);
    gld16(gA1 + kt, lA1);
    gld16(gB0 + kt, lB0);
    gld16(gB1 + kt, lB1);
    __syncthreads();
    s16x8 aF[2][2], bF[2][2];  // [tile][kstep]
#pragma unroll
    for (int i = 0; i < 2; i++)
#pragma unroll
      for (int u = 0; u < 2; u++) {
        aF[i][u] = *(const s16x8*)(As + (wr + i * 32 + r32) * 32 + u * 16 + ks);
        bF[i][u] = *(const s16x8*)(Bs + (wc + i * 32 + r32) * 32 + u * 16 + ks);
      }
#pragma unroll
    for (int u = 0; u < 2; u++)
#pragma unroll
      for (int i = 0; i < 2; i++)
#pragma unroll
        for (int j = 0; j < 2; j++)
          acc[i][j] = __builtin_amdgcn_mfma_f32_32x32x16_bf16(aF[i][u], bF[j][u], acc[i][j], 0, 0, 0);
    __syncthreads();
  }

  // epilogue: C/D map col=lane&31, row=(reg&3)+8*(reg>>2)+4*(lane>>5)
  const int rbase = 4 * (lane >> 5);
  float bsv[2];
#pragma unroll
  for (int j = 0; j < 2; j++) bsv[j] = bias[n0 + wc + j * 32 + r32];
#pragma unroll
  for (int i = 0; i < 2; i++)
#pragma unroll
    for (int j = 0; j < 2; j++)
#pragma unroll
      for (int reg = 0; reg < 16; reg++) {
        const size_t row = (size_t)(m0 + wr + i * 32 + rbase + (reg & 3) + 8 * (reg >> 2));
        const int col = n0 + wc + j * 32 + r32;
        float v = acc[i][j][reg] + bsv[j];
        if (flags & 1) v = gelu_f(v);
        if (flags & 2) v += res[row * N + col];
        if (flags & 4) ((unsigned short*)C)[row * N + col] = f2bf(v);
        else ((float*)C)[row * N + col] = v;
      }
}

// ---------- Hebbian phase A: per-chunk decayed outer-product sums ----------
__global__ __launch_bounds__(256) void k_heb_chunk(
    const unsigned short* __restrict__ qkv, const float* __restrict__ gam,
    float* __restrict__ U, float* __restrict__ Dc) {
  __shared__ float kw[4096];
  __shared__ float vS[4096];
  __shared__ float cum[64];
  const int bx = blockIdx.x;
  const int c = bx & 31, bh = bx >> 5, b = bh >> 3, h = bh & 7;
  const int t = threadIdx.x;
  const int n0 = c * 64;
  const size_t base = ((size_t)(b * Nn_ + n0)) * 1536 + h * 64;
#pragma unroll
  for (int l = 0; l < 2; l++) {
    const int idx8 = t + 256 * l;
    const int s = idx8 >> 3;
    const int d0 = (idx8 & 7) << 3;
    const size_t gi = base + (size_t)s * 1536 + d0;
    bf8_to_f(qkv + gi + 512, &kw[s * 64 + d0]);
    bf8_to_f(qkv + gi + 1024, &vS[s * 64 + d0]);
  }
  if (t < 64) {
    float val = 0.01f * gam[b * Nn_ + n0 + t];
#pragma unroll
    for (int off = 1; off < 64; off <<= 1) {
      const float o = __shfl_up(val, off, 64);
      if (t >= off) val += o;
    }
    cum[t] = val;
  }
  __syncthreads();
  const float total = cum[63];
#pragma unroll
  for (int l = 0; l < 16; l++) {
    const int idx = t + 256 * l;
    const int s = idx >> 6;
    kw[idx] *= 0.1f * __expf(cum[s] - total);
  }
  __syncthreads();
  const int td = (t & 15) << 2, te = (t >> 4) << 2;
  float acc[4][4];
#pragma unroll
  for (int i = 0; i < 4; i++)
#pragma unroll
    for (int j = 0; j < 4; j++) acc[i][j] = 0.0f;
  for (int s = 0; s < 64; s++) {
    const float4 kk = *(const float4*)&kw[s * 64 + td];
    const float4 vv = *(const float4*)&vS[s * 64 + te];
    const float ka[4] = {kk.x, kk.y, kk.z, kk.w};
    const float va[4] = {vv.x, vv.y, vv.z, vv.w};
#pragma unroll
    for (int i = 0; i < 4; i++)
#pragma unroll
      for (int j = 0; j < 4; j++) acc[i][j] = fmaf(ka[i], va[j], acc[i][j]);
  }
  float* Up = U + (size_t)bx * 4096;
#pragma unroll
  for (int i = 0; i < 4; i++)
#pragma unroll
    for (int j = 0; j < 4; j++) Up[(td + i) * 64 + te + j] = acc[i][j];
  if (t == 0) Dc[bx] = __expf(-total);
}

// ---------- Hebbian phase B: carry W across chunks (one thread per element) ----------
__global__ __launch_bounds__(256) void k_heb_scan(
    const float* __restrict__ U, const float* __restrict__ Dc, float* __restrict__ Win) {
  const int gid = blockIdx.x * 256 + threadIdx.x;   // 0..131071
  const int bh = gid >> 12, el = gid & 4095;
  float w = 0.0f;
#pragma unroll 4
  for (int c = 0; c < 32; c++) {
    const size_t idx = (((size_t)(bh * 32 + c)) << 12) + el;
    Win[idx] = w;
    w = Dc[bh * 32 + c] * w + U[idx];
  }
}

// ---------- Hebbian phase C: intra-chunk causal + inter-chunk q@W_in ----------
__global__ __launch_bounds__(256) void k_heb_out(
    const unsigned short* __restrict__ qkv, const float* __restrict__ gam,
    const float* __restrict__ Win, unsigned short* __restrict__ heb) {
  __shared__ float qS[4096];
  __shared__ float kT[4096];
  __shared__ float vS[4096];
  __shared__ float P[4096];
  const int bx = blockIdx.x;
  const int c = bx & 31, bh = bx >> 5, b = bh >> 3, h = bh & 7;
  const int t = threadIdx.x;
  const int n0 = c * 64;
  const size_t base = ((size_t)(b * Nn_ + n0)) * 1536 + h * 64;
#pragma unroll
  for (int l = 0; l < 2; l++) {
    const int idx8 = t + 256 * l;
    const int s = idx8 >> 3;
    const int d0 = (idx8 & 7) << 3;
    const size_t gi = base + (size_t)s * 1536 + d0;
    bf8_to_f(qkv + gi, &qS[s * 64 + d0]);
    bf8_to_f(qkv + gi + 1024, &vS[s * 64 + d0]);
    float tmp[8];
    bf8_to_f(qkv + gi + 512, tmp);
#pragma unroll
    for (int j = 0; j < 8; j++) kT[(d0 + j) * 64 + s] = tmp[j];
  }
  if (t < 64) {
    float val = 0.01f * gam[b * Nn_ + n0 + t];
#pragma unroll
    for (int off = 1; off < 64; off <<= 1) {
      const float o = __shfl_up(val, off, 64);
      if (t >= off) val += o;
    }
    P[t] = val;
  }
  __syncthreads();
  const int tr = (t >> 4) << 2;
  const int tc = (t & 15) << 2;
  float er[4], es[4];
#pragma unroll
  for (int r = 0; r < 4; r++) er[r] = __expf(-P[tr + r]);
#pragma unroll
  for (int j = 0; j < 4; j++) es[j] = 0.1f * __expf(P[tc + j]);
  __syncthreads();
  float acc[4][4];
#pragma unroll
  for (int i = 0; i < 4; i++)
#pragma unroll
    for (int j = 0; j < 4; j++) acc[i][j] = 0.0f;
  for (int d = 0; d < 64; d++) {
    const float4 kk = *(const float4*)&kT[d * 64 + tc];
    const float ka[4] = {kk.x, kk.y, kk.z, kk.w};
#pragma unroll
    for (int r = 0; r < 4; r++) {
      const float qv = qS[(tr + r) * 64 + d];
#pragma unroll
      for (int j = 0; j < 4; j++) acc[r][j] = fmaf(qv, ka[j], acc[r][j]);
    }
  }
#pragma unroll
  for (int r = 0; r < 4; r++)
#pragma unroll
    for (int j = 0; j < 4; j++) {
      const int tt = tr + r, ssi = tc + j;
      const float wgt = (ssi <= tt) ? er[r] * es[j] : 0.0f;
      P[tt * 64 + ssi] = acc[r][j] * wgt;
    }
  __syncthreads();
  const size_t wb = (size_t)bx * 4096;
#pragma unroll
  for (int l = 0; l < 16; l++) {
    const int idx = t + 256 * l;
    kT[idx] = Win[wb + idx];
  }
  __syncthreads();
  float o1[4][4], o2[4][4];
#pragma unroll
  for (int i = 0; i < 4; i++)
#pragma unroll
    for (int j = 0; j < 4; j++) { o1[i][j] = 0.0f; o2[i][j] = 0.0f; }
  for (int s = 0; s < 64; s++) {
    const float4 vv = *(const float4*)&vS[s * 64 + tc];
    const float4 ww = *(const float4*)&kT[s * 64 + tc];
    const float va[4] = {vv.x, vv.y, vv.z, vv.w};
    const float wa[4] = {ww.x, ww.y, ww.z, ww.w};
#pragma unroll
    for (int r = 0; r < 4; r++) {
      const float pv = P[(tr + r) * 64 + s];
      const float qv = qS[(tr + r) * 64 + s];
#pragma unroll
      for (int j = 0; j < 4; j++) {
        o1[r][j] = fmaf(pv, va[j], o1[r][j]);
        o2[r][j] = fmaf(qv, wa[j], o2[r][j]);
      }
    }
  }
#pragma unroll
  for (int r = 0; r < 4; r++) {
    const int n = n0 + tr + r;
    ushort4 pk;
    pk.x = f2bf(o1[r][0] + er[r] * o2[r][0]);
    pk.y = f2bf(o1[r][1] + er[r] * o2[r][1]);
    pk.z = f2bf(o1[r][2] + er[r] * o2[r][2]);
    pk.w = f2bf(o1[r][3] + er[r] * o2[r][3]);
    *(ushort4*)&heb[((size_t)b * Nn_ + n) * 512 + h * 64 + tc] = pk;
  }
}

extern "C" void kernel_launch(void* const* d_in, const int* in_sizes, int n_in,
                              void* d_out, int out_size, void* d_ws, size_t ws_size,
                              hipStream_t stream) {
  const float* x     = (const float*)d_in[0];
  const float* ln1g  = (const float*)d_in[1];
  const float* ln1b  = (const float*)d_in[2];
  const float* ln2g  = (const float*)d_in[3];
  const float* ln2b  = (const float*)d_in[4];
  const float* ln3g  = (const float*)d_in[5];
  const float* ln3b  = (const float*)d_in[6];
  const float* w_pot = (const float*)d_in[7];
  const float* b_pot = (const float*)d_in[8];
  const float* w_bk  = (const float*)d_in[9];
  const float* b_bk  = (const float*)d_in[10];
  const float* w_qkv = (const float*)d_in[11];
  const float* b_qkv = (const float*)d_in[12];
  const float* w_out = (const float*)d_in[13];
  const float* b_out = (const float*)d_in[14];
  const float* w_ff1 = (const float*)d_in[15];
  const float* b_ff1 = (const float*)d_in[16];
  const float* w_ff2 = (const float*)d_in[17];
  const float* b_ff2 = (const float*)d_in[18];
  float* out = (float*)d_out;
  float* ws = (float*)d_ws;

  // ---- workspace layout (float units), total 34,668,544 floats = 138.7 MB ----
  float* V   = ws;
  float* gam = V + 8192;
  float* aRe = gam + 8192;
  float* aIm = aRe + 8192;
  float* bRe = aIm + 8192;
  float* bIm = bRe + 8192;
  float* Dc  = bIm + 8192;
  float* HID = ws + 65536;             // 16.78M f32 (67.1MB): x1 (first 8.39M) + qkv
                                       //   (next 6.29M) early; ff hidden (full) late
  float* x1   = HID;                   // 8.39M f32
  unsigned short* qkvb = (unsigned short*)(HID + 8388608);  // 12.58M shorts
  unsigned short* hid  = (unsigned short*)HID;              // 8192x4096 bf16 (ff phase)
  float* RC   = HID + 16777216;        // 8.39M f32: U+Win, later x2
  float* U    = RC;
  float* Win  = RC + 4194304;
  float* x2   = RC;
  float* RD   = RC + 8388608;          // 4.19M f32: xn2/heb/xn3 (bf16)
  unsigned short* xnb = (unsigned short*)RD;
  unsigned short* heb = (unsigned short*)RD;
  unsigned short* wE  = (unsigned short*)(RD + 4194304);
  unsigned short* wqkvT = wE;                    // 1536x1024
  unsigned short* woutT = wqkvT + 1572864;       // 1024x512
  unsigned short* wff1T = woutT + 524288;        // 4096x1024
  unsigned short* wff2T = wff1T + 4194304;       // 1024x4096

  // weight transposes (fp32 KxN -> bf16 NxK)
  k_wt<<<dim3(1536 / 32, 1024 / 32), 256, 0, stream>>>(w_qkv, wqkvT, 1024, 1536);
  k_wt<<<dim3(1024 / 32, 512 / 32), 256, 0, stream>>>(w_out, woutT, 512, 1024);
  k_wt<<<dim3(4096 / 32, 1024 / 32), 256, 0, stream>>>(w_ff1, wff1T, 1024, 4096);
  k_wt<<<dim3(1024 / 32, 4096 / 32), 256, 0, stream>>>(w_ff2, wff2T, 4096, 1024);

  k_ln_pot<<<Tt, 256, 0, stream>>>(x, ln1g, ln1b, w_pot, b_pot, V, gam);
  k_cf_par<<<8, 64, 0, stream>>>(V, gam, aRe, aIm, bRe, bIm);
  k_bk_add<<<Tt, 256, 0, stream>>>(x, aRe, aIm, bRe, bIm, V, gam, w_bk, b_bk, x1);
  k_ln_bf<<<Tt, 256, 0, stream>>>(x1, ln2g, ln2b, xnb);
  // qkv: (8192x1024)@(1024x1536) -> bf16
  k_gemm_bf<<<dim3(12, 64), 256, 0, stream>>>(xnb, wqkvT, b_qkv, nullptr, qkvb,
                                              8192, 1024, 1536, 4);
  k_heb_chunk<<<1024, 256, 0, stream>>>(qkvb, gam, U, Dc);
  k_heb_scan<<<512, 256, 0, stream>>>(U, Dc, Win);
  k_heb_out<<<1024, 256, 0, stream>>>(qkvb, gam, Win, heb);
  // out-proj: (8192x512)@(512x1024) + x1 -> f32 x2
  k_gemm_bf<<<dim3(8, 64), 256, 0, stream>>>(heb, woutT, b_out, x1, x2,
                                             8192, 512, 1024, 2);
  k_ln_bf<<<Tt, 256, 0, stream>>>(x2, ln3g, ln3b, xnb);
  // ff1: (8192x1024)@(1024x4096) gelu -> bf16 hid (overlays dead x1+qkv)
  k_gemm_bf<<<dim3(32, 64), 256, 0, stream>>>(xnb, wff1T, b_ff1, nullptr, hid,
                                              8192, 1024, 4096, 1 | 4);
  // ff2: (8192x4096)@(4096x1024) + x2 -> f32 out
  k_gemm_bf<<<dim3(8, 64), 256, 0, stream>>>(hid, wff2T, b_ff2, x2, out,
                                             8192, 4096, 1024, 2);
}

// Round 5
// 533.406 us; speedup vs baseline: 6.5448x; 1.0491x over previous
//
#include <hip/hip_runtime.h>

#define Bn 4
#define Nn_ 2048
#define Dd 1024
#define Hh 8
#define HDd 64
#define Tt 8192   // Bn*Nn_

typedef short s16x8 __attribute__((ext_vector_type(8)));
typedef float f32x4 __attribute__((ext_vector_type(4)));
typedef float f32x16 __attribute__((ext_vector_type(16)));

__device__ __forceinline__ unsigned short f2bf(float f) {
  unsigned u = __float_as_uint(f);
  return (unsigned short)((u + 0x7fffu + ((u >> 16) & 1u)) >> 16);
}

__device__ __forceinline__ void bf8_to_f(const unsigned short* p, float* o) {
  const uint4 u = *(const uint4*)p;
  o[0] = __uint_as_float(u.x << 16);
  o[1] = __uint_as_float(u.x & 0xffff0000u);
  o[2] = __uint_as_float(u.y << 16);
  o[3] = __uint_as_float(u.y & 0xffff0000u);
  o[4] = __uint_as_float(u.z << 16);
  o[5] = __uint_as_float(u.z & 0xffff0000u);
  o[6] = __uint_as_float(u.w << 16);
  o[7] = __uint_as_float(u.w & 0xffff0000u);
}

__device__ __forceinline__ void gld16(const void* g, void* l) {
  __builtin_amdgcn_global_load_lds(
      (const __attribute__((address_space(1))) unsigned int*)(uintptr_t)g,
      (__attribute__((address_space(3))) unsigned int*)(uintptr_t)l, 16, 0, 0);
}

__device__ __forceinline__ void block_reduce2(float& a, float& b, float* sc) {
#pragma unroll
  for (int off = 32; off > 0; off >>= 1) {
    a += __shfl_down(a, off, 64);
    b += __shfl_down(b, off, 64);
  }
  __syncthreads();
  if ((threadIdx.x & 63) == 0) { int wid = threadIdx.x >> 6; sc[wid] = a; sc[4 + wid] = b; }
  __syncthreads();
  a = sc[0] + sc[1] + sc[2] + sc[3];
  b = sc[4] + sc[5] + sc[6] + sc[7];
}

__device__ __forceinline__ float gelu_f(float u) {
  const float c = 0.7978845608028654f * (u + 0.044715f * u * u * u);
  const float e = __expf(2.0f * c);
  const float th = 1.0f - 2.0f / (1.0f + e);
  return 0.5f * u * (1.0f + th);
}

// ---------- weight convert+transpose: W (KxN f32) -> WT (NxK bf16) ----------
__global__ __launch_bounds__(256) void k_wt(const float* __restrict__ W,
                                            unsigned short* __restrict__ WT, int K, int N) {
  __shared__ float tile[32][33];
  const int n0 = blockIdx.x * 32, k0 = blockIdx.y * 32;
  const int tx = threadIdx.x & 31, ty = threadIdx.x >> 5;  // ty 0..7
#pragma unroll
  for (int i = 0; i < 4; i++) {
    const int kk = ty + i * 8;
    tile[kk][tx] = W[(size_t)(k0 + kk) * N + n0 + tx];
  }
  __syncthreads();
#pragma unroll
  for (int i = 0; i < 4; i++) {
    const int nn = ty + i * 8;
    WT[(size_t)(n0 + nn) * K + k0 + tx] = f2bf(tile[tx][nn]);
  }
}

// ---------- LN1 + potential projection (V, gamma) ----------
__global__ __launch_bounds__(256) void k_ln_pot(
    const float* __restrict__ x, const float* __restrict__ g, const float* __restrict__ bt,
    const float* __restrict__ w_pot, const float* __restrict__ b_pot,
    float* __restrict__ V, float* __restrict__ gam) {
  __shared__ float sc[8];
  const int m = blockIdx.x, t = threadIdx.x;
  const float4 xv = ((const float4*)(x + (size_t)m * Dd))[t];
  float s = xv.x + xv.y + xv.z + xv.w;
  float ss = fmaf(xv.x, xv.x, fmaf(xv.y, xv.y, fmaf(xv.z, xv.z, xv.w * xv.w)));
  block_reduce2(s, ss, sc);
  const float mean = s * (1.0f / Dd);
  const float var = ss * (1.0f / Dd) - mean * mean;
  const float rs = rsqrtf(var + 1e-5f);
  const float4 gv = ((const float4*)g)[t];
  const float4 bv = ((const float4*)bt)[t];
  const float xn0 = (xv.x - mean) * rs * gv.x + bv.x;
  const float xn1 = (xv.y - mean) * rs * gv.y + bv.y;
  const float xn2 = (xv.z - mean) * rs * gv.z + bv.z;
  const float xn3 = (xv.w - mean) * rs * gv.w + bv.w;
  const float4 wp0 = ((const float4*)w_pot)[t * 2];
  const float4 wp1 = ((const float4*)w_pot)[t * 2 + 1];
  float s0 = xn0 * wp0.x + xn1 * wp0.z + xn2 * wp1.x + xn3 * wp1.z;
  float s1 = xn0 * wp0.y + xn1 * wp0.w + xn2 * wp1.y + xn3 * wp1.w;
  block_reduce2(s0, s1, sc);
  if (t == 0) {
    V[m] = s0 + b_pot[0];
    const float p1 = s1 + b_pot[1];
    const float sp = fmaxf(p1, 0.0f) + log1pf(expf(-fabsf(p1)));
    gam[m] = sp + 0.1f;
  }
}

// ---------- parallel continued fraction scan (Mobius matrix scan + replay) ----------
__global__ void k_cf_par(const float* __restrict__ V, const float* __restrict__ gam,
                         float* __restrict__ aRe, float* __restrict__ aIm,
                         float* __restrict__ bRe, float* __restrict__ bIm) {
  const int b = blockIdx.x >> 1, dir = blockIdx.x & 1;
  const int l = threadIdx.x;  // 0..63
  const float* Vb = V + b * Nn_;
  const float* gb = gam + b * Nn_;
  float m[8] = {1.f, 0.f, 0.f, 0.f, 0.f, 0.f, 1.f, 0.f};
#pragma unroll 4
  for (int s = 0; s < 32; s++) {
    const int j = l * 32 + s;
    const int i = dir ? (Nn_ - 1 - j) : j;
    const float dre = Vb[i] + 2.0f, dim = -gb[i];
    const float n00r = dre * m[0] - dim * m[1] - m[4];
    const float n00i = dre * m[1] + dim * m[0] - m[5];
    const float n01r = dre * m[2] - dim * m[3] - m[6];
    const float n01i = dre * m[3] + dim * m[2] - m[7];
    m[4] = m[0]; m[5] = m[1]; m[6] = m[2]; m[7] = m[3];
    m[0] = n00r; m[1] = n00i; m[2] = n01r; m[3] = n01i;
    const float rr = 1.0f / (fabsf(m[0]) + fabsf(m[1]) + fabsf(m[4]) + fabsf(m[5]));
#pragma unroll
    for (int q = 0; q < 8; q++) m[q] *= rr;
  }
#pragma unroll
  for (int off = 1; off < 64; off <<= 1) {
    float p[8];
#pragma unroll
    for (int q = 0; q < 8; q++) p[q] = __shfl_up(m[q], off, 64);
    if (l < off) { p[0] = 1.f; p[1] = 0.f; p[2] = 0.f; p[3] = 0.f;
                   p[4] = 0.f; p[5] = 0.f; p[6] = 1.f; p[7] = 0.f; }
    float c[8];
    c[0] = m[0] * p[0] - m[1] * p[1] + m[2] * p[4] - m[3] * p[5];
    c[1] = m[0] * p[1] + m[1] * p[0] + m[2] * p[5] + m[3] * p[4];
    c[2] = m[0] * p[2] - m[1] * p[3] + m[2] * p[6] - m[3] * p[7];
    c[3] = m[0] * p[3] + m[1] * p[2] + m[2] * p[7] + m[3] * p[6];
    c[4] = m[4] * p[0] - m[5] * p[1] + m[6] * p[4] - m[7] * p[5];
    c[5] = m[4] * p[1] + m[5] * p[0] + m[6] * p[5] + m[7] * p[4];
    c[6] = m[4] * p[2] - m[5] * p[3] + m[6] * p[6] - m[7] * p[7];
    c[7] = m[4] * p[3] + m[5] * p[2] + m[6] * p[7] + m[7] * p[6];
    const float rr = 1.0f / (fabsf(c[0]) + fabsf(c[1]) + fabsf(c[4]) + fabsf(c[5]));
#pragma unroll
    for (int q = 0; q < 8; q++) m[q] = c[q] * rr;
  }
  float e[8];
#pragma unroll
  for (int q = 0; q < 8; q++) e[q] = __shfl_up(m[q], 1, 64);
  if (l == 0) { e[0] = 1.f; e[1] = 0.f; e[4] = 0.f; e[5] = 0.f; }
  const float inr = 1.0f / (e[0] * e[0] + e[1] * e[1]);
  float pr = (e[4] * e[0] + e[5] * e[1]) * inr;
  float pi = (e[5] * e[0] - e[4] * e[1]) * inr;
  float* oR = dir ? bRe : aRe;
  float* oI = dir ? bIm : aIm;
#pragma unroll 4
  for (int s = 0; s < 32; s++) {
    const int j = l * 32 + s;
    const int i = dir ? (Nn_ - 1 - j) : j;
    const float dre = Vb[i] + 2.0f, dim = -gb[i];
    const float ar = dre - pr, ai = dim - pi;
    oR[b * Nn_ + i] = ar; oI[b * Nn_ + i] = ai;
    const float r = 1.0f / (ar * ar + ai * ai);
    pr = ar * r; pi = -ai * r;
  }
}

// ---------- x1 = x + [G.re,G.im] @ w_bk + b_bk ----------
__global__ __launch_bounds__(256) void k_bk_add(
    const float* __restrict__ x, const float* __restrict__ aRe, const float* __restrict__ aIm,
    const float* __restrict__ bRe, const float* __restrict__ bIm,
    const float* __restrict__ V, const float* __restrict__ gam,
    const float* __restrict__ w_bk, const float* __restrict__ b_bk, float* __restrict__ x1) {
  const int m = blockIdx.x, t = threadIdx.x;
  const float dre = V[m] + 2.0f, dim = -gam[m];
  const float nr = aRe[m] + bRe[m] - dre;
  const float ni = aIm[m] + bIm[m] - dim;
  const float r = 1.0f / (nr * nr + ni * ni);
  const float Gre = nr * r, Gim = -ni * r;
  const float4 xv = ((const float4*)(x + (size_t)m * Dd))[t];
  const float4 w0 = ((const float4*)w_bk)[t];
  const float4 w1 = ((const float4*)(w_bk + Dd))[t];
  const float4 bb = ((const float4*)b_bk)[t];
  float4 o;
  o.x = xv.x + Gre * w0.x + Gim * w1.x + bb.x;
  o.y = xv.y + Gre * w0.y + Gim * w1.y + bb.y;
  o.z = xv.z + Gre * w0.z + Gim * w1.z + bb.z;
  o.w = xv.w + Gre * w0.w + Gim * w1.w + bb.w;
  ((float4*)(x1 + (size_t)m * Dd))[t] = o;
}

// ---------- layernorm -> bf16 output ----------
__global__ __launch_bounds__(256) void k_ln_bf(
    const float* __restrict__ x, const float* __restrict__ g, const float* __restrict__ bt,
    unsigned short* __restrict__ y) {
  __shared__ float sc[8];
  const int m = blockIdx.x, t = threadIdx.x;
  const float4 xv = ((const float4*)(x + (size_t)m * Dd))[t];
  float s = xv.x + xv.y + xv.z + xv.w;
  float ss = fmaf(xv.x, xv.x, fmaf(xv.y, xv.y, fmaf(xv.z, xv.z, xv.w * xv.w)));
  block_reduce2(s, ss, sc);
  const float mean = s * (1.0f / Dd);
  const float var = ss * (1.0f / Dd) - mean * mean;
  const float rs = rsqrtf(var + 1e-5f);
  const float4 gv = ((const float4*)g)[t];
  const float4 bv = ((const float4*)bt)[t];
  ushort4 pk;
  pk.x = f2bf((xv.x - mean) * rs * gv.x + bv.x);
  pk.y = f2bf((xv.y - mean) * rs * gv.y + bv.y);
  pk.z = f2bf((xv.z - mean) * rs * gv.z + bv.z);
  pk.w = f2bf((xv.w - mean) * rs * gv.w + bv.w);
  ((ushort4*)(y + (size_t)m * Dd))[t] = pk;
}

// ---------- bf16 MFMA GEMM (32x32x16), XOR-swizzled LDS, XCD-aware grid ----------
// flags: 1=gelu, 2=add fp32 res, 4=store bf16 (else fp32)
// grid: 1-D, nb*mb blocks; g=(bid&7)*(total/8)+(bid>>3); m=g/nb, n=g%nb
__global__ __launch_bounds__(256) void k_gemm_bf(
    const unsigned short* __restrict__ A, const unsigned short* __restrict__ BT,
    const float* __restrict__ bias, const float* __restrict__ res,
    void* __restrict__ C, int M, int K, int N, int flags, int nb) {
  __shared__ unsigned short As[128 * 32];
  __shared__ unsigned short Bs[128 * 32];
  const int t = threadIdx.x;
  const int bid = blockIdx.x;
  const int g = (bid & 7) * (gridDim.x >> 3) + (bid >> 3);
  const int n0 = (g % nb) * 128;
  const int m0 = (g / nb) * 128;
  const int lane = t & 63;
  const int w = t >> 6;
  const int wr = (w >> 1) * 64, wc = (w & 1) * 64;  // wave's 64x64 quadrant
  const int r32 = lane & 31;        // row/col within a 32-tile
  const int ls = lane >> 5;         // k-half select
  const int swz = (lane ^ (lane >> 2)) & 3;  // read-side XOR swizzle

  // staging pointers; source column permuted so LDS slot s holds chunk s^swzR
  const int srow = t >> 2;
  const int scol = (((t & 3) ^ ((srow ^ (srow >> 2)) & 3))) * 8;
  const unsigned short* gA0 = A + (size_t)(m0 + srow) * K + scol;
  const unsigned short* gA1 = A + (size_t)(m0 + srow + 64) * K + scol;
  const unsigned short* gB0 = BT + (size_t)(n0 + srow) * K + scol;
  const unsigned short* gB1 = BT + (size_t)(n0 + srow + 64) * K + scol;
  unsigned short* lA0 = As + t * 8;
  unsigned short* lA1 = As + (t + 256) * 8;
  unsigned short* lB0 = Bs + t * 8;
  unsigned short* lB1 = Bs + (t + 256) * 8;

  f32x16 acc[2][2];
#pragma unroll
  for (int i = 0; i < 2; i++)
#pragma unroll
    for (int j = 0; j < 2; j++)
#pragma unroll
      for (int q = 0; q < 16; q++) acc[i][j][q] = 0.0f;

  for (int kt = 0; kt < K; kt += 32) {
    gld16(gA0 + kt, lA0);
    gld16(gA1 + kt, lA1);
    gld16(gB0 + kt, lB0);
    gld16(gB1 + kt, lB1);
    __syncthreads();
    s16x8 aF[2][2], bF[2][2];  // [tile][kstep]
#pragma unroll
    for (int i = 0; i < 2; i++)
#pragma unroll
      for (int u = 0; u < 2; u++) {
        const int ch = (((u * 2 + ls) ^ swz)) * 8;
        aF[i][u] = *(const s16x8*)(As + (wr + i * 32 + r32) * 32 + ch);
        bF[i][u] = *(const s16x8*)(Bs + (wc + i * 32 + r32) * 32 + ch);
      }
#pragma unroll
    for (int u = 0; u < 2; u++)
#pragma unroll
      for (int i = 0; i < 2; i++)
#pragma unroll
        for (int j = 0; j < 2; j++)
          acc[i][j] = __builtin_amdgcn_mfma_f32_32x32x16_bf16(aF[i][u], bF[j][u], acc[i][j], 0, 0, 0);
    __syncthreads();
  }

  // epilogue: C/D map col=lane&31, row=(reg&3)+8*(reg>>2)+4*(lane>>5)
  const int rbase = 4 * ls;
  float bsv[2];
#pragma unroll
  for (int j = 0; j < 2; j++) bsv[j] = bias[n0 + wc + j * 32 + r32];
#pragma unroll
  for (int i = 0; i < 2; i++)
#pragma unroll
    for (int j = 0; j < 2; j++)
#pragma unroll
      for (int reg = 0; reg < 16; reg++) {
        const size_t row = (size_t)(m0 + wr + i * 32 + rbase + (reg & 3) + 8 * (reg >> 2));
        const int col = n0 + wc + j * 32 + r32;
        float v = acc[i][j][reg] + bsv[j];
        if (flags & 1) v = gelu_f(v);
        if (flags & 2) v += res[row * N + col];
        if (flags & 4) ((unsigned short*)C)[row * N + col] = f2bf(v);
        else ((float*)C)[row * N + col] = v;
      }
}

// ---------- Hebbian phase A: per-chunk decayed outer-product sums ----------
__global__ __launch_bounds__(256) void k_heb_chunk(
    const unsigned short* __restrict__ qkv, const float* __restrict__ gam,
    float* __restrict__ U, float* __restrict__ Dc) {
  __shared__ float kw[4096];
  __shared__ float vS[4096];
  __shared__ float cum[64];
  const int bx = blockIdx.x;
  const int c = bx & 31, bh = bx >> 5, b = bh >> 3, h = bh & 7;
  const int t = threadIdx.x;
  const int n0 = c * 64;
  const size_t base = ((size_t)(b * Nn_ + n0)) * 1536 + h * 64;
#pragma unroll
  for (int l = 0; l < 2; l++) {
    const int idx8 = t + 256 * l;
    const int s = idx8 >> 3;
    const int d0 = (idx8 & 7) << 3;
    const size_t gi = base + (size_t)s * 1536 + d0;
    bf8_to_f(qkv + gi + 512, &kw[s * 64 + d0]);
    bf8_to_f(qkv + gi + 1024, &vS[s * 64 + d0]);
  }
  if (t < 64) {
    float val = 0.01f * gam[b * Nn_ + n0 + t];
#pragma unroll
    for (int off = 1; off < 64; off <<= 1) {
      const float o = __shfl_up(val, off, 64);
      if (t >= off) val += o;
    }
    cum[t] = val;
  }
  __syncthreads();
  const float total = cum[63];
#pragma unroll
  for (int l = 0; l < 16; l++) {
    const int idx = t + 256 * l;
    const int s = idx >> 6;
    kw[idx] *= 0.1f * __expf(cum[s] - total);
  }
  __syncthreads();
  const int td = (t & 15) << 2, te = (t >> 4) << 2;
  float acc[4][4];
#pragma unroll
  for (int i = 0; i < 4; i++)
#pragma unroll
    for (int j = 0; j < 4; j++) acc[i][j] = 0.0f;
  for (int s = 0; s < 64; s++) {
    const float4 kk = *(const float4*)&kw[s * 64 + td];
    const float4 vv = *(const float4*)&vS[s * 64 + te];
    const float ka[4] = {kk.x, kk.y, kk.z, kk.w};
    const float va[4] = {vv.x, vv.y, vv.z, vv.w};
#pragma unroll
    for (int i = 0; i < 4; i++)
#pragma unroll
      for (int j = 0; j < 4; j++) acc[i][j] = fmaf(ka[i], va[j], acc[i][j]);
  }
  float* Up = U + (size_t)bx * 4096;
#pragma unroll
  for (int i = 0; i < 4; i++)
#pragma unroll
    for (int j = 0; j < 4; j++) Up[(td + i) * 64 + te + j] = acc[i][j];
  if (t == 0) Dc[bx] = __expf(-total);
}

// ---------- Hebbian phase B: carry W across chunks (one thread per element) ----------
__global__ __launch_bounds__(256) void k_heb_scan(
    const float* __restrict__ U, const float* __restrict__ Dc, float* __restrict__ Win) {
  const int gid = blockIdx.x * 256 + threadIdx.x;   // 0..131071
  const int bh = gid >> 12, el = gid & 4095;
  float w = 0.0f;
#pragma unroll 4
  for (int c = 0; c < 32; c++) {
    const size_t idx = (((size_t)(bh * 32 + c)) << 12) + el;
    Win[idx] = w;
    w = Dc[bh * 32 + c] * w + U[idx];
  }
}

// ---------- Hebbian phase C: intra-chunk causal + inter-chunk q@W_in ----------
__global__ __launch_bounds__(256) void k_heb_out(
    const unsigned short* __restrict__ qkv, const float* __restrict__ gam,
    const float* __restrict__ Win, unsigned short* __restrict__ heb) {
  __shared__ float qS[4096];
  __shared__ float kT[4096];
  __shared__ float vS[4096];
  __shared__ float P[4096];
  const int bx = blockIdx.x;
  const int c = bx & 31, bh = bx >> 5, b = bh >> 3, h = bh & 7;
  const int t = threadIdx.x;
  const int n0 = c * 64;
  const size_t base = ((size_t)(b * Nn_ + n0)) * 1536 + h * 64;
#pragma unroll
  for (int l = 0; l < 2; l++) {
    const int idx8 = t + 256 * l;
    const int s = idx8 >> 3;
    const int d0 = (idx8 & 7) << 3;
    const size_t gi = base + (size_t)s * 1536 + d0;
    bf8_to_f(qkv + gi, &qS[s * 64 + d0]);
    bf8_to_f(qkv + gi + 1024, &vS[s * 64 + d0]);
    float tmp[8];
    bf8_to_f(qkv + gi + 512, tmp);
#pragma unroll
    for (int j = 0; j < 8; j++) kT[(d0 + j) * 64 + s] = tmp[j];
  }
  if (t < 64) {
    float val = 0.01f * gam[b * Nn_ + n0 + t];
#pragma unroll
    for (int off = 1; off < 64; off <<= 1) {
      const float o = __shfl_up(val, off, 64);
      if (t >= off) val += o;
    }
    P[t] = val;
  }
  __syncthreads();
  const int tr = (t >> 4) << 2;
  const int tc = (t & 15) << 2;
  float er[4], es[4];
#pragma unroll
  for (int r = 0; r < 4; r++) er[r] = __expf(-P[tr + r]);
#pragma unroll
  for (int j = 0; j < 4; j++) es[j] = 0.1f * __expf(P[tc + j]);
  __syncthreads();
  float acc[4][4];
#pragma unroll
  for (int i = 0; i < 4; i++)
#pragma unroll
    for (int j = 0; j < 4; j++) acc[i][j] = 0.0f;
  for (int d = 0; d < 64; d++) {
    const float4 kk = *(const float4*)&kT[d * 64 + tc];
    const float ka[4] = {kk.x, kk.y, kk.z, kk.w};
#pragma unroll
    for (int r = 0; r < 4; r++) {
      const float qv = qS[(tr + r) * 64 + d];
#pragma unroll
      for (int j = 0; j < 4; j++) acc[r][j] = fmaf(qv, ka[j], acc[r][j]);
    }
  }
#pragma unroll
  for (int r = 0; r < 4; r++)
#pragma unroll
    for (int j = 0; j < 4; j++) {
      const int tt = tr + r, ssi = tc + j;
      const float wgt = (ssi <= tt) ? er[r] * es[j] : 0.0f;
      P[tt * 64 + ssi] = acc[r][j] * wgt;
    }
  __syncthreads();
  const size_t wb = (size_t)bx * 4096;
#pragma unroll
  for (int l = 0; l < 16; l++) {
    const int idx = t + 256 * l;
    kT[idx] = Win[wb + idx];
  }
  __syncthreads();
  float o1[4][4], o2[4][4];
#pragma unroll
  for (int i = 0; i < 4; i++)
#pragma unroll
    for (int j = 0; j < 4; j++) { o1[i][j] = 0.0f; o2[i][j] = 0.0f; }
  for (int s = 0; s < 64; s++) {
    const float4 vv = *(const float4*)&vS[s * 64 + tc];
    const float4 ww = *(const float4*)&kT[s * 64 + tc];
    const float va[4] = {vv.x, vv.y, vv.z, vv.w};
    const float wa[4] = {ww.x, ww.y, ww.z, ww.w};
#pragma unroll
    for (int r = 0; r < 4; r++) {
      const float pv = P[(tr + r) * 64 + s];
      const float qv = qS[(tr + r) * 64 + s];
#pragma unroll
      for (int j = 0; j < 4; j++) {
        o1[r][j] = fmaf(pv, va[j], o1[r][j]);
        o2[r][j] = fmaf(qv, wa[j], o2[r][j]);
      }
    }
  }
#pragma unroll
  for (int r = 0; r < 4; r++) {
    const int n = n0 + tr + r;
    ushort4 pk;
    pk.x = f2bf(o1[r][0] + er[r] * o2[r][0]);
    pk.y = f2bf(o1[r][1] + er[r] * o2[r][1]);
    pk.z = f2bf(o1[r][2] + er[r] * o2[r][2]);
    pk.w = f2bf(o1[r][3] + er[r] * o2[r][3]);
    *(ushort4*)&heb[((size_t)b * Nn_ + n) * 512 + h * 64 + tc] = pk;
  }
}

extern "C" void kernel_launch(void* const* d_in, const int* in_sizes, int n_in,
                              void* d_out, int out_size, void* d_ws, size_t ws_size,
                              hipStream_t stream) {
  const float* x     = (const float*)d_in[0];
  const float* ln1g  = (const float*)d_in[1];
  const float* ln1b  = (const float*)d_in[2];
  const float* ln2g  = (const float*)d_in[3];
  const float* ln2b  = (const float*)d_in[4];
  const float* ln3g  = (const float*)d_in[5];
  const float* ln3b  = (const float*)d_in[6];
  const float* w_pot = (const float*)d_in[7];
  const float* b_pot = (const float*)d_in[8];
  const float* w_bk  = (const float*)d_in[9];
  const float* b_bk  = (const float*)d_in[10];
  const float* w_qkv = (const float*)d_in[11];
  const float* b_qkv = (const float*)d_in[12];
  const float* w_out = (const float*)d_in[13];
  const float* b_out = (const float*)d_in[14];
  const float* w_ff1 = (const float*)d_in[15];
  const float* b_ff1 = (const float*)d_in[16];
  const float* w_ff2 = (const float*)d_in[17];
  const float* b_ff2 = (const float*)d_in[18];
  float* out = (float*)d_out;
  float* ws = (float*)d_ws;

  // ---- workspace layout (float units), total 34,668,544 floats = 138.7 MB ----
  float* V   = ws;
  float* gam = V + 8192;
  float* aRe = gam + 8192;
  float* aIm = aRe + 8192;
  float* bRe = aIm + 8192;
  float* bIm = bRe + 8192;
  float* Dc  = bIm + 8192;
  float* HID = ws + 65536;             // 16.78M f32 (67.1MB): x1 + qkv early; ff hidden late
  float* x1   = HID;                   // 8.39M f32
  unsigned short* qkvb = (unsigned short*)(HID + 8388608);  // 12.58M shorts
  unsigned short* hid  = (unsigned short*)HID;              // 8192x4096 bf16 (ff phase)
  float* RC   = HID + 16777216;        // 8.39M f32: U+Win, later x2
  float* U    = RC;
  float* Win  = RC + 4194304;
  float* x2   = RC;
  float* RD   = RC + 8388608;          // 4.19M f32: xn2/heb/xn3 (bf16)
  unsigned short* xnb = (unsigned short*)RD;
  unsigned short* heb = (unsigned short*)RD;
  unsigned short* wE  = (unsigned short*)(RD + 4194304);
  unsigned short* wqkvT = wE;                    // 1536x1024
  unsigned short* woutT = wqkvT + 1572864;       // 1024x512
  unsigned short* wff1T = woutT + 524288;        // 4096x1024
  unsigned short* wff2T = wff1T + 4194304;       // 1024x4096

  // weight transposes (fp32 KxN -> bf16 NxK)
  k_wt<<<dim3(1536 / 32, 1024 / 32), 256, 0, stream>>>(w_qkv, wqkvT, 1024, 1536);
  k_wt<<<dim3(1024 / 32, 512 / 32), 256, 0, stream>>>(w_out, woutT, 512, 1024);
  k_wt<<<dim3(4096 / 32, 1024 / 32), 256, 0, stream>>>(w_ff1, wff1T, 1024, 4096);
  k_wt<<<dim3(1024 / 32, 4096 / 32), 256, 0, stream>>>(w_ff2, wff2T, 4096, 1024);

  k_ln_pot<<<Tt, 256, 0, stream>>>(x, ln1g, ln1b, w_pot, b_pot, V, gam);
  k_cf_par<<<8, 64, 0, stream>>>(V, gam, aRe, aIm, bRe, bIm);
  k_bk_add<<<Tt, 256, 0, stream>>>(x, aRe, aIm, bRe, bIm, V, gam, w_bk, b_bk, x1);
  k_ln_bf<<<Tt, 256, 0, stream>>>(x1, ln2g, ln2b, xnb);
  // qkv: (8192x1024)@(1024x1536) -> bf16   [nb=12, 768 blocks]
  k_gemm_bf<<<768, 256, 0, stream>>>(xnb, wqkvT, b_qkv, nullptr, qkvb,
                                     8192, 1024, 1536, 4, 12);
  k_heb_chunk<<<1024, 256, 0, stream>>>(qkvb, gam, U, Dc);
  k_heb_scan<<<512, 256, 0, stream>>>(U, Dc, Win);
  k_heb_out<<<1024, 256, 0, stream>>>(qkvb, gam, Win, heb);
  // out-proj: (8192x512)@(512x1024) + x1 -> f32 x2   [nb=8, 512 blocks]
  k_gemm_bf<<<512, 256, 0, stream>>>(heb, woutT, b_out, x1, x2,
                                     8192, 512, 1024, 2, 8);
  k_ln_bf<<<Tt, 256, 0, stream>>>(x2, ln3g, ln3b, xnb);
  // ff1: (8192x1024)@(1024x4096) gelu -> bf16 hid   [nb=32, 2048 blocks]
  k_gemm_bf<<<2048, 256, 0, stream>>>(xnb, wff1T, b_ff1, nullptr, hid,
                                      8192, 1024, 4096, 1 | 4, 32);
  // ff2: (8192x4096)@(4096x1024) + x2 -> f32 out   [nb=8, 512 blocks]
  k_gemm_bf<<<512, 256, 0, stream>>>(hid, wff2T, b_ff2, x2, out,
                                     8192, 4096, 1024, 2, 8);
}